// Round 8
// baseline (335.155 us; speedup 1.0000x reference)
//
#include <hip/hip_runtime.h>

// MHA forward: B=2, S=2048, D=1024, H=16, HD=64. Inputs f32, mask int32,
// OUTPUT f32. Intermediates bf16.
//
// Round 16: GEMM k-loop -> true T3+T4 (counted vmcnt + RAW s_barrier).
//   Diagnosis R12-R15: __syncthreads() ALWAYS emits s_waitcnt vmcnt(0) ->
//   every prefetch variant was drained at the next barrier (zero overlap).
//   Fix: __builtin_amdgcn_s_barrier() (no implicit vmcnt drain) + 2-deep
//   reg-staged pipeline with static reg sets / static LDS buffer parity.
//   Compiler's auto-waitcnt before ds_write is then vmcnt(4) (counted),
//   giving each tile's loads a full iteration (~500-800cy) to land.
//   Barrier safety: each STORES targets the buffer whose reads completed
//   before the PREVIOUS barrier (lgkmcnt(0) precedes every barrier).
//  - QKV z-fused grid (32,8,3) = 3 blocks/CU (dbuf 33KB, ~150 VGPR).
//  - proj 128x128 grid (32,8), same loop, f32 out.
//  - cvt_all / attn_mfma (R10, 58.3us) / combine unchanged.

#define BB 2
#define SS 2048
#define DD 1024
#define HH 16
#define HDD 64
#define NEG_BIG (-1.0e30f)
#define QSCL 0.18033688011112042f  // 0.125 * log2(e)

typedef __attribute__((ext_vector_type(8))) short short8;
typedef __attribute__((ext_vector_type(4))) float floatx4;
typedef unsigned int u32;

__device__ __forceinline__ ushort f2bf(float f) {  // RNE
    unsigned u = __float_as_uint(f);
    u += 0x7fffu + ((u >> 16) & 1u);
    return (ushort)(u >> 16);
}
__device__ __forceinline__ unsigned pk2(float a, float b) {
    return ((unsigned)f2bf(b) << 16) | (unsigned)f2bf(a);
}
__device__ __forceinline__ unsigned cvtpk(float a, float b) {  // lo=a, hi=b, RNE
    unsigned r;
    asm("v_cvt_pk_bf16_f32 %0, %1, %2" : "=v"(r) : "v"(a), "v"(b));
    return r;
}
__device__ __forceinline__ void unpack8(const uint4 u, float* d) {
    d[0] = __uint_as_float(u.x << 16);
    d[1] = __uint_as_float(u.x & 0xffff0000u);
    d[2] = __uint_as_float(u.y << 16);
    d[3] = __uint_as_float(u.y & 0xffff0000u);
    d[4] = __uint_as_float(u.z << 16);
    d[5] = __uint_as_float(u.z & 0xffff0000u);
    d[6] = __uint_as_float(u.w << 16);
    d[7] = __uint_as_float(u.w & 0xffff0000u);
}
// Raw barrier: lgkmcnt(0) ensures our LDS ops are done/visible; the raw
// s_barrier does NOT drain vmcnt -> prefetch loads stay in flight across it.
__device__ __forceinline__ void bar() {
    asm volatile("s_waitcnt lgkmcnt(0)" ::: "memory");
    __builtin_amdgcn_s_barrier();
    asm volatile("" ::: "memory");
}

// ---------------- f32 -> bf16 conversion (x, Wq, Wk, Wv, Wp) ----------------
// Wq is pre-scaled by QSCL (attention scale + log2e folded into Q).
__global__ __launch_bounds__(256) void cvt_all(
    const float* __restrict__ x, const float* __restrict__ wq,
    const float* __restrict__ wk, const float* __restrict__ wv,
    const float* __restrict__ wp,
    ushort* __restrict__ dst, ushort* __restrict__ wp_dst)
{
    const size_t flat = ((size_t)blockIdx.x * 256 + threadIdx.x) * 8;
    const float* s;
    ushort* d = dst + flat;
    size_t off;
    float scl = 1.0f;
    if (flat < (size_t)4194304)      { s = x;  off = flat; }
    else if (flat < (size_t)5242880) { s = wq; off = flat - 4194304; scl = QSCL; }
    else if (flat < (size_t)6291456) { s = wk; off = flat - 5242880; }
    else if (flat < (size_t)7340032) { s = wv; off = flat - 6291456; }
    else { s = wp; off = flat - 7340032; d = wp_dst + off; }
    const float4 a = ((const float4*)(s + off))[0];
    const float4 b = ((const float4*)(s + off))[1];
    uint4 u;
    u.x = pk2(a.x * scl, a.y * scl); u.y = pk2(a.z * scl, a.w * scl);
    u.z = pk2(b.x * scl, b.y * scl); u.w = pk2(b.z * scl, b.w * scl);
    *(uint4*)d = u;
}

// ---------------- QKV GEMM: T3+T4 pipeline ----------------
// z=0: Q (swapped, bias*QSCL, out (B,H,S,HD))
// z=1: K (swapped, out (B,H,S,HD))
// z=2: V (unswapped, out (B,H,HD,S))
__global__ __launch_bounds__(256, 3) void gemm_qkv_t34(
    const ushort* __restrict__ A,
    const ushort* __restrict__ W0, const ushort* __restrict__ W1,
    const ushort* __restrict__ W2,
    const float* __restrict__ B0, const float* __restrict__ B1,
    const float* __restrict__ B2,
    ushort* __restrict__ O0, ushort* __restrict__ O1, ushort* __restrict__ O2)
{
    __shared__ ushort As[2][128 * 32];
    __shared__ ushort Bs[2][128 * 32];
    __shared__ float bias_s[128];

    const int z = blockIdx.z;
    const ushort* W = (z == 0) ? W0 : (z == 1 ? W1 : W2);
    const float* bias = (z == 0) ? B0 : (z == 1 ? B1 : B2);
    ushort* out = (z == 0) ? O0 : (z == 1 ? O1 : O2);
    const bool isv = (z == 2);

    const int tid = threadIdx.x;
    const int bm = blockIdx.x * 128, bn = blockIdx.y * 128;
    const int wave = tid >> 6, lane = tid & 63, quad = lane >> 4, lm = lane & 15;
    const int wm = wave >> 1, wn = wave & 1;
    const int r0 = tid >> 2, c0 = (tid & 3) * 8;

    if (tid < 128) {
        float bb = bias[bn + tid];
        if (z == 0) bb *= QSCL;
        bias_s[tid] = bb;
    }

    const floatx4 zz = {0.f, 0.f, 0.f, 0.f};
    floatx4 acc[4][4];
#pragma unroll
    for (int i = 0; i < 4; ++i)
#pragma unroll
        for (int j = 0; j < 4; ++j) acc[i][j] = zz;

    const ushort* ap = A + (size_t)(bm + r0) * DD + c0;
    const ushort* wpp = W + (size_t)(bn + r0) * DD + c0;

    uint4 pA0, pA1, pA2, pA3, pB0, pB1, pB2, pB3;

#define LOADS(s, K0)                                              \
    do {                                                          \
        s##0 = *(const uint4*)(ap + (K0));                        \
        s##1 = *(const uint4*)(ap + (size_t)64 * DD + (K0));      \
        s##2 = *(const uint4*)(wpp + (K0));                       \
        s##3 = *(const uint4*)(wpp + (size_t)64 * DD + (K0));     \
    } while (0)
#define STORES(buf, s)                                            \
    do {                                                          \
        *(uint4*)&As[buf][r0 * 32 + c0] = s##0;                   \
        *(uint4*)&As[buf][(64 + r0) * 32 + c0] = s##1;            \
        *(uint4*)&Bs[buf][r0 * 32 + c0] = s##2;                   \
        *(uint4*)&Bs[buf][(64 + r0) * 32 + c0] = s##3;            \
    } while (0)
#define COMPUTE(buf)                                                          \
    do {                                                                      \
        short8 af[4], bf[4];                                                  \
        _Pragma("unroll")                                                     \
        for (int i = 0; i < 4; ++i)                                           \
            af[i] = *(const short8*)&As[buf][(wm * 64 + i * 16 + lm) * 32 + quad * 8]; \
        _Pragma("unroll")                                                     \
        for (int j = 0; j < 4; ++j)                                           \
            bf[j] = *(const short8*)&Bs[buf][(wn * 64 + j * 16 + lm) * 32 + quad * 8]; \
        if (isv) {                                                            \
            _Pragma("unroll")                                                 \
            for (int i = 0; i < 4; ++i)                                       \
                _Pragma("unroll")                                             \
                for (int j = 0; j < 4; ++j)                                   \
                    acc[i][j] = __builtin_amdgcn_mfma_f32_16x16x32_bf16(      \
                        af[i], bf[j], acc[i][j], 0, 0, 0);                    \
        } else {                                                              \
            _Pragma("unroll")                                                 \
            for (int i = 0; i < 4; ++i)                                       \
                _Pragma("unroll")                                             \
                for (int j = 0; j < 4; ++j)                                   \
                    acc[i][j] = __builtin_amdgcn_mfma_f32_16x16x32_bf16(      \
                        bf[j], af[i], acc[i][j], 0, 0, 0);                    \
        }                                                                     \
    } while (0)

    // prologue: tile0 staged; tile1 in flight
    LOADS(pA, 0);
    STORES(0, pA);   // compiler inserts vmcnt(0) here (once)
    bar();
    LOADS(pA, 32);   // tile1 -> pA, stays in flight across barriers

    for (int k0 = 0; k0 < DD; k0 += 64) {
        // half 1: compute even tile (buf0); pA holds next (odd) tile
        if (k0 + 64 < DD) LOADS(pB, k0 + 64);   // tile+2 in flight
        COMPUTE(0);
        STORES(1, pA);                          // auto vmcnt(4): pB newer
        bar();
        // half 2: compute odd tile (buf1); pB holds tile+2
        if (k0 + 96 < DD) LOADS(pA, k0 + 96);   // tile+3 in flight
        COMPUTE(1);
        if (k0 + 64 < DD) STORES(0, pB);        // auto vmcnt(4): pA newer
        bar();
    }
#undef LOADS
#undef STORES
#undef COMPUTE

#pragma unroll
    for (int i = 0; i < 4; ++i) {
#pragma unroll
        for (int j = 0; j < 4; ++j) {
            if (isv) {  // unswapped: regs = 4 consecutive m (=s)
                const int n = bn + wn * 64 + j * 16 + lm;
                const int m0 = bm + wm * 64 + i * 16 + quad * 4;
                const int b = m0 >> 11, s0 = m0 & 2047;
                const float bb = bias_s[n - bn];
                ushort4 v;
                v.x = f2bf(acc[i][j][0] + bb);
                v.y = f2bf(acc[i][j][1] + bb);
                v.z = f2bf(acc[i][j][2] + bb);
                v.w = f2bf(acc[i][j][3] + bb);
                *(ushort4*)(out + ((size_t)(b * DD + n)) * SS + s0) = v;
            } else {    // swapped: regs = 4 consecutive n
                const int nl = wn * 64 + j * 16 + quad * 4;
                const int n = bn + nl;
                const int m = bm + wm * 64 + i * 16 + lm;
                const int b = m >> 11, s = m & 2047, h = n >> 6, hd = n & 63;
                ushort4 v;
                v.x = f2bf(acc[i][j][0] + bias_s[nl + 0]);
                v.y = f2bf(acc[i][j][1] + bias_s[nl + 1]);
                v.z = f2bf(acc[i][j][2] + bias_s[nl + 2]);
                v.w = f2bf(acc[i][j][3] + bias_s[nl + 3]);
                *(ushort4*)(out + (((size_t)(b * HH + h) * SS) + s) * HDD + hd) = v;
            }
        }
    }
}

// ---------------- proj GEMM: 128x128, T3+T4 pipeline, f32 out --------------
__global__ __launch_bounds__(256, 2) void gemm_proj_t34(
    const ushort* __restrict__ A, const ushort* __restrict__ W,
    const float* __restrict__ bias, float* __restrict__ out)
{
    __shared__ ushort As[2][128 * 32];
    __shared__ ushort Bs[2][128 * 32];
    __shared__ float bias_s[128];

    const int tid = threadIdx.x;
    const int bm = blockIdx.x * 128, bn = blockIdx.y * 128;
    const int wave = tid >> 6, lane = tid & 63, quad = lane >> 4, lm = lane & 15;
    const int wm = wave >> 1, wn = wave & 1;
    const int r0 = tid >> 2, c0 = (tid & 3) * 8;

    if (tid < 128) bias_s[tid] = bias[bn + tid];

    const floatx4 zz = {0.f, 0.f, 0.f, 0.f};
    floatx4 acc[4][4];
#pragma unroll
    for (int i = 0; i < 4; ++i)
#pragma unroll
        for (int j = 0; j < 4; ++j) acc[i][j] = zz;

    const ushort* ap = A + (size_t)(bm + r0) * DD + c0;
    const ushort* wpp = W + (size_t)(bn + r0) * DD + c0;

    uint4 pA0, pA1, pA2, pA3, pB0, pB1, pB2, pB3;

#define LOADS(s, K0)                                              \
    do {                                                          \
        s##0 = *(const uint4*)(ap + (K0));                        \
        s##1 = *(const uint4*)(ap + (size_t)64 * DD + (K0));      \
        s##2 = *(const uint4*)(wpp + (K0));                       \
        s##3 = *(const uint4*)(wpp + (size_t)64 * DD + (K0));     \
    } while (0)
#define STORES(buf, s)                                            \
    do {                                                          \
        *(uint4*)&As[buf][r0 * 32 + c0] = s##0;                   \
        *(uint4*)&As[buf][(64 + r0) * 32 + c0] = s##1;            \
        *(uint4*)&Bs[buf][r0 * 32 + c0] = s##2;                   \
        *(uint4*)&Bs[buf][(64 + r0) * 32 + c0] = s##3;            \
    } while (0)
#define COMPUTE(buf)                                                          \
    do {                                                                      \
        short8 af[4], bf[4];                                                  \
        _Pragma("unroll")                                                     \
        for (int i = 0; i < 4; ++i)                                           \
            af[i] = *(const short8*)&As[buf][(wm * 64 + i * 16 + lm) * 32 + quad * 8]; \
        _Pragma("unroll")                                                     \
        for (int j = 0; j < 4; ++j)                                           \
            bf[j] = *(const short8*)&Bs[buf][(wn * 64 + j * 16 + lm) * 32 + quad * 8]; \
        _Pragma("unroll")                                                     \
        for (int i = 0; i < 4; ++i)                                           \
            _Pragma("unroll")                                                 \
            for (int j = 0; j < 4; ++j)                                       \
                acc[i][j] = __builtin_amdgcn_mfma_f32_16x16x32_bf16(          \
                    bf[j], af[i], acc[i][j], 0, 0, 0);                        \
    } while (0)

    LOADS(pA, 0);
    STORES(0, pA);
    bar();
    LOADS(pA, 32);

    for (int k0 = 0; k0 < DD; k0 += 64) {
        if (k0 + 64 < DD) LOADS(pB, k0 + 64);
        COMPUTE(0);
        STORES(1, pA);
        bar();
        if (k0 + 96 < DD) LOADS(pA, k0 + 96);
        COMPUTE(1);
        if (k0 + 64 < DD) STORES(0, pB);
        bar();
    }
#undef LOADS
#undef STORES
#undef COMPUTE

#pragma unroll
    for (int i = 0; i < 4; ++i) {
#pragma unroll
        for (int j = 0; j < 4; ++j) {
            const int nl = wn * 64 + j * 16 + quad * 4;
            const int n = bn + nl;
            const int m = bm + wm * 64 + i * 16 + lm;
            float4 v;
            v.x = acc[i][j][0] + bias_s[nl + 0];
            v.y = acc[i][j][1] + bias_s[nl + 1];
            v.z = acc[i][j][2] + bias_s[nl + 2];
            v.w = acc[i][j][3] + bias_s[nl + 3];
            *(float4*)(out + (size_t)m * DD + n) = v;
        }
    }
}

// ---------------- Attention: swapped MFMA, split-K x2 (R10) ----------------
// Q,K: (B*H,S,HD) bf16 (Q pre-scaled by QSCL -> logits are log2-domain).
// Vt: (B*H,HD,S) bf16.
// Opart: 2 x (B,S,D) bf16 unnormalized. lbuf: 2 x (B*H*S) f32.
__global__ __launch_bounds__(256) void attn_mfma(
    const ushort* __restrict__ Q, const ushort* __restrict__ K,
    const ushort* __restrict__ Vt, const int* __restrict__ am,
    ushort* __restrict__ Opart, float* __restrict__ lbuf)
{
    __shared__ ushort Ks[64 * 72];
    __shared__ ushort Vts[64 * 72];
    __shared__ ushort Ps[4][32 * 72];
    __shared__ int amk_s[64];

    const int tid = threadIdx.x;
    const int wq = tid >> 6, lane = tid & 63, quad = lane >> 4, lm = lane & 15;
    const int bh = blockIdx.y, b = bh >> 4, h = bh & 15;
    // Balance: same-CU blocks are {same x, both b, both splits}. qt = b?x:15-x
    // pairs workloads (x+1)+(16-x)=17 tiles/split on every CU.
    const int qt = b ? (int)blockIdx.x : (int)(gridDim.x - 1 - blockIdx.x);
    const int split = blockIdx.z;
    const size_t base = (size_t)bh * SS * HDD;
    const size_t tbase = (size_t)bh * HDD * SS;
    const int* amrow = am + b * SS;
    const int q0 = qt * 128 + wq * 32;

    short8 qf[2][2];
#pragma unroll
    for (int sub = 0; sub < 2; ++sub) {
        const ushort* qp = Q + base + (size_t)(q0 + sub * 16 + lm) * HDD + quad * 8;
        qf[sub][0] = *(const short8*)qp;
        qf[sub][1] = *(const short8*)(qp + 32);
    }
    int amq[2];
#pragma unroll
    for (int sub = 0; sub < 2; ++sub) amq[sub] = amrow[q0 + sub * 16 + lm];
    const bool allq = __all(amq[0] != 0 && amq[1] != 0);

    const floatx4 zz = {0.f, 0.f, 0.f, 0.f};
    floatx4 o_acc[2][4];
#pragma unroll
    for (int sub = 0; sub < 2; ++sub)
#pragma unroll
        for (int n2 = 0; n2 < 4; ++n2) o_acc[sub][n2] = zz;
    float l_lane[2] = {0.f, 0.f};

    const int sr = tid >> 2, sc = (tid & 3) * 16;
    const int ktmax = 2 * qt + 1;

    // ---- prologue: stage first tile ----
    uint4 kra, krb, vra, vrb;
    int amr = 1;
    {
        const ushort* kp = K + base + (size_t)(split * 64 + sr) * HDD + sc;
        kra = ((const uint4*)kp)[0]; krb = ((const uint4*)kp)[1];
        const ushort* vp = Vt + tbase + (size_t)sr * SS + split * 64 + sc;
        vra = ((const uint4*)vp)[0]; vrb = ((const uint4*)vp)[1];
        if (tid < 64) amr = amrow[split * 64 + tid];
    }
    *(uint4*)&Ks[sr * 72 + sc] = kra;
    *(uint4*)&Ks[sr * 72 + sc + 8] = krb;
    *(uint4*)&Vts[sr * 72 + sc] = vra;
    *(uint4*)&Vts[sr * 72 + sc + 8] = vrb;
    if (tid < 64) amk_s[tid] = amr;
    __syncthreads();

    for (int kt = split; kt <= ktmax; kt += 2) {
        const int nxt = kt + 2;
        const bool have_nxt = nxt <= ktmax;
        // T14: issue next tile's global loads now; LDS writes after barrier.
        if (have_nxt) {
            const ushort* kp = K + base + (size_t)(nxt * 64 + sr) * HDD + sc;
            kra = ((const uint4*)kp)[0]; krb = ((const uint4*)kp)[1];
            const ushort* vp = Vt + tbase + (size_t)sr * SS + nxt * 64 + sc;
            vra = ((const uint4*)vp)[0]; vrb = ((const uint4*)vp)[1];
            if (tid < 64) amr = amrow[nxt * 64 + tid];
        }

        // ---- S^T = K Q^T (swapped): regs = 4 consecutive t ----
        const bool allk = (__ballot(amk_s[lane] != 0) == ~0ull);
        const bool fast = allk & allq & ((kt * 64 + 63) <= q0);
        if (fast) {
#pragma unroll
            for (int nt = 0; nt < 4; ++nt) {
                const short8 kf0 = *(const short8*)&Ks[(nt * 16 + lm) * 72 + quad * 8];
                const short8 kf1 = *(const short8*)&Ks[(nt * 16 + lm) * 72 + 32 + quad * 8];
#pragma unroll
                for (int sub = 0; sub < 2; ++sub) {
                    floatx4 s = zz;
                    s = __builtin_amdgcn_mfma_f32_16x16x32_bf16(kf0, qf[sub][0], s, 0, 0, 0);
                    s = __builtin_amdgcn_mfma_f32_16x16x32_bf16(kf1, qf[sub][1], s, 0, 0, 0);
                    const float e0 = exp2f(fminf(s[0], 40.f));
                    const float e1 = exp2f(fminf(s[1], 40.f));
                    const float e2 = exp2f(fminf(s[2], 40.f));
                    const float e3 = exp2f(fminf(s[3], 40.f));
                    l_lane[sub] += (e0 + e1) + (e2 + e3);
                    uint2 pv;
                    pv.x = cvtpk(e0, e1); pv.y = cvtpk(e2, e3);
                    *(uint2*)&Ps[wq][(sub * 16 + lm) * 72 + nt * 16 + quad * 4] = pv;
                }
            }
        } else {
#pragma unroll
            for (int nt = 0; nt < 4; ++nt) {
                const short8 kf0 = *(const short8*)&Ks[(nt * 16 + lm) * 72 + quad * 8];
                const short8 kf1 = *(const short8*)&Ks[(nt * 16 + lm) * 72 + 32 + quad * 8];
                const int4 amk4 = *(const int4*)&amk_s[nt * 16 + quad * 4];
#pragma unroll
                for (int sub = 0; sub < 2; ++sub) {
                    floatx4 s = zz;
                    s = __builtin_amdgcn_mfma_f32_16x16x32_bf16(kf0, qf[sub][0], s, 0, 0, 0);
                    s = __builtin_amdgcn_mfma_f32_16x16x32_bf16(kf1, qf[sub][1], s, 0, 0, 0);
                    const int qg = q0 + sub * 16 + lm;
                    const int t0 = kt * 64 + nt * 16 + quad * 4;
                    const bool mq = amq[sub] != 0;
                    const bool ok0 = amk4.x && mq && (t0 + 0 <= qg);
                    const bool ok1 = amk4.y && mq && (t0 + 1 <= qg);
                    const bool ok2 = amk4.z && mq && (t0 + 2 <= qg);
                    const bool ok3 = amk4.w && mq && (t0 + 3 <= qg);
                    const float e0 = exp2f(fminf(ok0 ? s[0] : NEG_BIG, 40.f));
                    const float e1 = exp2f(fminf(ok1 ? s[1] : NEG_BIG, 40.f));
                    const float e2 = exp2f(fminf(ok2 ? s[2] : NEG_BIG, 40.f));
                    const float e3 = exp2f(fminf(ok3 ? s[3] : NEG_BIG, 40.f));
                    l_lane[sub] += (e0 + e1) + (e2 + e3);
                    uint2 pv;
                    pv.x = cvtpk(e0, e1); pv.y = cvtpk(e2, e3);
                    *(uint2*)&Ps[wq][(sub * 16 + lm) * 72 + nt * 16 + quad * 4] = pv;
                }
            }
        }

        // ---- O^T += V^T P^T (swapped): regs = 4 consecutive hd ----
        short8 af[2][2];
#pragma unroll
        for (int sub = 0; sub < 2; ++sub) {
            af[sub][0] = *(const short8*)&Ps[wq][(sub * 16 + lm) * 72 + quad * 8];
            af[sub][1] = *(const short8*)&Ps[wq][(sub * 16 + lm) * 72 + 32 + quad * 8];
        }
#pragma unroll
        for (int n2 = 0; n2 < 4; ++n2) {
            const short8 vf0 = *(const short8*)&Vts[(n2 * 16 + lm) * 72 + quad * 8];
            const short8 vf1 = *(const short8*)&Vts[(n2 * 16 + lm) * 72 + 32 + quad * 8];
#pragma unroll
            for (int sub = 0; sub < 2; ++sub) {
                o_acc[sub][n2] = __builtin_amdgcn_mfma_f32_16x16x32_bf16(
                    vf0, af[sub][0], o_acc[sub][n2], 0, 0, 0);
                o_acc[sub][n2] = __builtin_amdgcn_mfma_f32_16x16x32_bf16(
                    vf1, af[sub][1], o_acc[sub][n2], 0, 0, 0);
            }
        }

        if (have_nxt) {
            __syncthreads();  // all waves done reading Ks/Vts/amk_s
            *(uint4*)&Ks[sr * 72 + sc] = kra;
            *(uint4*)&Ks[sr * 72 + sc + 8] = krb;
            *(uint4*)&Vts[sr * 72 + sc] = vra;
            *(uint4*)&Vts[sr * 72 + sc + 8] = vrb;
            if (tid < 64) amk_s[tid] = amr;
            __syncthreads();  // next tile ready
        }
    }

    // ---- l: sum across quads (lane's l covers its t-subset; q = lm) ----
#pragma unroll
    for (int sub = 0; sub < 2; ++sub) {
        float l = l_lane[sub];
        l += __shfl_xor(l, 16);
        l += __shfl_xor(l, 32);
        if (quad == 0)
            lbuf[(size_t)split * (BB * HH * SS) + (size_t)bh * SS + q0 + sub * 16 + lm] = l;
        // ---- epilogue: unnormalized O, packed 4 consecutive hd ----
        const int srow = q0 + sub * 16 + lm;
#pragma unroll
        for (int n2 = 0; n2 < 4; ++n2) {
            uint2 v;
            v.x = cvtpk(o_acc[sub][n2][0], o_acc[sub][n2][1]);
            v.y = cvtpk(o_acc[sub][n2][2], o_acc[sub][n2][3]);
            *(uint2*)(Opart + (size_t)split * (BB * SS * DD)
                        + ((size_t)(b * SS + srow)) * DD + h * HDD + n2 * 16 + quad * 4) = v;
        }
    }
}

// ---------------- combine: A = (O0 + O1) / (l0 + l1), bf16 ----------------
__global__ __launch_bounds__(256) void combine(
    const ushort* __restrict__ Opart, const float* __restrict__ lbuf,
    ushort* __restrict__ Aout)
{
    const size_t e = ((size_t)blockIdx.x * 256 + threadIdx.x) * 8;
    const int m = (int)(e >> 10);
    const int col = (int)(e & 1023);
    const int b = m >> 11, s = m & 2047, h = col >> 6;
    const float l = lbuf[(b * HH + h) * SS + s]
                  + lbuf[BB * HH * SS + (b * HH + h) * SS + s];
    const float inv = l > 0.f ? 1.f / l : 0.f;
    const uint4 u0 = *(const uint4*)(Opart + e);
    const uint4 u1 = *(const uint4*)(Opart + (size_t)BB * SS * DD + e);
    float f0[8], f1[8];
    unpack8(u0, f0);
    unpack8(u1, f1);
    uint4 o;
    o.x = pk2((f0[0] + f1[0]) * inv, (f0[1] + f1[1]) * inv);
    o.y = pk2((f0[2] + f1[2]) * inv, (f0[3] + f1[3]) * inv);
    o.z = pk2((f0[4] + f1[4]) * inv, (f0[5] + f1[5]) * inv);
    o.w = pk2((f0[6] + f1[6]) * inv, (f0[7] + f1[7]) * inv);
    *(uint4*)(Aout + e) = o;
}

extern "C" void kernel_launch(void* const* d_in, const int* in_sizes, int n_in,
                              void* d_out, int out_size, void* d_ws, size_t ws_size,
                              hipStream_t stream) {
    const float* x  = (const float*)d_in[0];
    const int*   am = (const int*)d_in[1];
    const float* Wq = (const float*)d_in[2];
    const float* bq = (const float*)d_in[3];
    const float* Wk = (const float*)d_in[4];
    const float* bk = (const float*)d_in[5];
    const float* Wv = (const float*)d_in[6];
    const float* bv = (const float*)d_in[7];
    const float* Wp = (const float*)d_in[8];
    const float* bp = (const float*)d_in[9];
    float* out = (float*)d_out;

    const size_t elems = (size_t)BB * HH * SS * HDD;  // 4M
    ushort* q_ws = (ushort*)d_ws;                 // Q; later combined A
    ushort* k_ws = q_ws + elems;
    ushort* v_ws = k_ws + elems;                  // V^T (B,H,HD,S)
    float*  lbuf = (float*)(v_ws + elems);        // 2 x 256 KB in a_ws slot
    ushort* wpb  = (ushort*)(lbuf + 2 * BB * HH * SS);  // bf16 Wp (2 MB)

    // d_out scratch: bf16 x (4M) + Wq/Wk/Wv (1M each); later attn partials
    ushort* xb  = (ushort*)d_out;
    ushort* wqb = xb + 4194304;
    ushort* wkb = wqb + 1048576;
    ushort* wvb = wkb + 1048576;

    cvt_all<<<4096, 256, 0, stream>>>(x, Wq, Wk, Wv, Wp, xb, wpb);

    gemm_qkv_t34<<<dim3(32, 8, 3), 256, 0, stream>>>(
        xb, wqb, wkb, wvb, bq, bk, bv, q_ws, k_ws, v_ws);

    attn_mfma<<<dim3(SS / 128, BB * HH, 2), 256, 0, stream>>>(
        q_ws, k_ws, v_ws, am, (ushort*)d_out, lbuf);

    combine<<<2048, 256, 0, stream>>>((const ushort*)d_out, lbuf, q_ws);

    gemm_proj_t34<<<dim3(32, 8), 256, 0, stream>>>(q_ws, wpb, bp, out);
}

// Round 9
// 232.895 us; speedup vs baseline: 1.4391x; 1.4391x over previous
//
#include <hip/hip_runtime.h>

// MHA forward: B=2, S=2048, D=1024, H=16, HD=64. Inputs f32, mask int32,
// OUTPUT f32. Intermediates bf16.
//
// Round 17: fix the measured WRITE amplification (126->360 MB vs 24 logical).
//   Epilogue stores were 8B ushort4 scattered at 128B/4KB strides -> partial
//   64B-line writes (write-allocate + repeated writebacks). Re-tile waves:
//   - Q/K (swapped): wave owns 32 m-rows x full n=128 (j 0..7): stores are
//     4-quad x 8B = 32B contiguous segments (adjacent j merge to 64B+).
//   - V (unswapped): wave owns 32 n-rows x full m=128 (i 0..7): 32B segments.
//   - proj: 64x128 tile, wave owns 16 m-rows x full n: float4 x 4 quads =
//     FULL 64B line per store group.
//   K-loop stays R12's m97-style dma16 + 2 __syncthreads (proven; 98us even
//   with the broken epilogue). No barrier-semantics games (R13-R16 lesson).
//  - cvt_all / attn_mfma (R10, 58.3us) / combine unchanged.

#define BB 2
#define SS 2048
#define DD 1024
#define HH 16
#define HDD 64
#define NEG_BIG (-1.0e30f)
#define QSCL 0.18033688011112042f  // 0.125 * log2(e)

typedef __attribute__((ext_vector_type(8))) short short8;
typedef __attribute__((ext_vector_type(4))) float floatx4;
typedef unsigned int u32;
#define AS_GLOBAL __attribute__((address_space(1)))
#define AS_LDS    __attribute__((address_space(3)))

__device__ __forceinline__ ushort f2bf(float f) {  // RNE
    unsigned u = __float_as_uint(f);
    u += 0x7fffu + ((u >> 16) & 1u);
    return (ushort)(u >> 16);
}
__device__ __forceinline__ unsigned pk2(float a, float b) {
    return ((unsigned)f2bf(b) << 16) | (unsigned)f2bf(a);
}
__device__ __forceinline__ unsigned cvtpk(float a, float b) {  // lo=a, hi=b, RNE
    unsigned r;
    asm("v_cvt_pk_bf16_f32 %0, %1, %2" : "=v"(r) : "v"(a), "v"(b));
    return r;
}
__device__ __forceinline__ void unpack8(const uint4 u, float* d) {
    d[0] = __uint_as_float(u.x << 16);
    d[1] = __uint_as_float(u.x & 0xffff0000u);
    d[2] = __uint_as_float(u.y << 16);
    d[3] = __uint_as_float(u.y & 0xffff0000u);
    d[4] = __uint_as_float(u.z << 16);
    d[5] = __uint_as_float(u.z & 0xffff0000u);
    d[6] = __uint_as_float(u.w << 16);
    d[7] = __uint_as_float(u.w & 0xffff0000u);
}
__device__ __forceinline__ void dma16(void* lds, const void* g) {
    __builtin_amdgcn_global_load_lds((const AS_GLOBAL u32*)g, (AS_LDS u32*)lds,
                                     16, 0, 0);
}

// ---------------- f32 -> bf16 conversion (x, Wq, Wk, Wv, Wp) ----------------
// Wq is pre-scaled by QSCL (attention scale + log2e folded into Q).
__global__ __launch_bounds__(256) void cvt_all(
    const float* __restrict__ x, const float* __restrict__ wq,
    const float* __restrict__ wk, const float* __restrict__ wv,
    const float* __restrict__ wp,
    ushort* __restrict__ dst, ushort* __restrict__ wp_dst)
{
    const size_t flat = ((size_t)blockIdx.x * 256 + threadIdx.x) * 8;
    const float* s;
    ushort* d = dst + flat;
    size_t off;
    float scl = 1.0f;
    if (flat < (size_t)4194304)      { s = x;  off = flat; }
    else if (flat < (size_t)5242880) { s = wq; off = flat - 4194304; scl = QSCL; }
    else if (flat < (size_t)6291456) { s = wk; off = flat - 5242880; }
    else if (flat < (size_t)7340032) { s = wv; off = flat - 6291456; }
    else { s = wp; off = flat - 7340032; d = wp_dst + off; }
    const float4 a = ((const float4*)(s + off))[0];
    const float4 b = ((const float4*)(s + off))[1];
    uint4 u;
    u.x = pk2(a.x * scl, a.y * scl); u.y = pk2(a.z * scl, a.w * scl);
    u.z = pk2(b.x * scl, b.y * scl); u.w = pk2(b.z * scl, b.w * scl);
    *(uint4*)d = u;
}

// ---------------- QKV GEMM: m97-style staging, line-friendly epilogue ------
// z=0: Q (swapped, bias*QSCL, out (B,H,S,HD))
// z=1: K (swapped, out (B,H,S,HD))
// z=2: V (unswapped, out (B,H,HD,S))
// Swapped tiling: wave owns m in [wave*32, wave*32+32) (i=0,1), full n via
//   j=0..7. Lane: m = bm+wave*32+i*16+lm, n = bn+j*16+quad*4+r.
// V tiling: wave owns n in [wave*32, +32) (j=0,1), full m via i=0..7.
//   Lane: n = bn+wave*32+j*16+lm, m = bm+i*16+quad*4+r.
__global__ __launch_bounds__(256) void gemm_qkv_wa(
    const ushort* __restrict__ A,
    const ushort* __restrict__ W0, const ushort* __restrict__ W1,
    const ushort* __restrict__ W2,
    const float* __restrict__ B0, const float* __restrict__ B1,
    const float* __restrict__ B2,
    ushort* __restrict__ O0, ushort* __restrict__ O1, ushort* __restrict__ O2)
{
    __shared__ ushort As[128 * 32];
    __shared__ ushort Bs[128 * 32];
    __shared__ float bias_s[128];

    const int z = blockIdx.z;
    const ushort* W = (z == 0) ? W0 : (z == 1 ? W1 : W2);
    const float* bias = (z == 0) ? B0 : (z == 1 ? B1 : B2);
    ushort* out = (z == 0) ? O0 : (z == 1 ? O1 : O2);
    const bool isv = (z == 2);

    const int tid = threadIdx.x;
    const int bm = blockIdx.x * 128, bn = blockIdx.y * 128;
    const int wave = tid >> 6, lane = tid & 63, quad = lane >> 4, lm = lane & 15;
    const int r0 = tid >> 2, c0 = (tid & 3) * 8;

    if (tid < 128) {
        float bb = bias[bn + tid];
        if (z == 0) bb *= QSCL;
        bias_s[tid] = bb;
    }

    const floatx4 zz = {0.f, 0.f, 0.f, 0.f};
    floatx4 acc[16];
#pragma unroll
    for (int i = 0; i < 16; ++i) acc[i] = zz;

    for (int k0 = 0; k0 < DD; k0 += 32) {
        __syncthreads();
        dma16(&As[r0 * 32 + c0], A + (size_t)(bm + r0) * DD + k0 + c0);
        dma16(&As[(64 + r0) * 32 + c0], A + (size_t)(bm + 64 + r0) * DD + k0 + c0);
        dma16(&Bs[r0 * 32 + c0], W + (size_t)(bn + r0) * DD + k0 + c0);
        dma16(&Bs[(64 + r0) * 32 + c0], W + (size_t)(bn + 64 + r0) * DD + k0 + c0);
        __syncthreads();

        if (isv) {
            const short8 bf0 = *(const short8*)&Bs[(wave * 32 + lm) * 32 + quad * 8];
            const short8 bf1 = *(const short8*)&Bs[(wave * 32 + 16 + lm) * 32 + quad * 8];
#pragma unroll
            for (int i = 0; i < 8; ++i) {
                const short8 af = *(const short8*)&As[(i * 16 + lm) * 32 + quad * 8];
                acc[i * 2 + 0] = __builtin_amdgcn_mfma_f32_16x16x32_bf16(
                    af, bf0, acc[i * 2 + 0], 0, 0, 0);
                acc[i * 2 + 1] = __builtin_amdgcn_mfma_f32_16x16x32_bf16(
                    af, bf1, acc[i * 2 + 1], 0, 0, 0);
            }
        } else {
            const short8 af0 = *(const short8*)&As[(wave * 32 + lm) * 32 + quad * 8];
            const short8 af1 = *(const short8*)&As[(wave * 32 + 16 + lm) * 32 + quad * 8];
#pragma unroll
            for (int j = 0; j < 8; ++j) {
                const short8 bf = *(const short8*)&Bs[(j * 16 + lm) * 32 + quad * 8];
                acc[j] = __builtin_amdgcn_mfma_f32_16x16x32_bf16(
                    bf, af0, acc[j], 0, 0, 0);
                acc[8 + j] = __builtin_amdgcn_mfma_f32_16x16x32_bf16(
                    bf, af1, acc[8 + j], 0, 0, 0);
            }
        }
    }

    if (isv) {
        // V: n-row per lane, 4 consecutive s per reg; 32B contiguous/instr.
        const int b = bm >> 11, sbase = bm & 2047;
#pragma unroll
        for (int j = 0; j < 2; ++j) {
            const int n = bn + wave * 32 + j * 16 + lm;
            const float bb = bias_s[n - bn];
            ushort* orow = out + ((size_t)(b * DD + n)) * SS;
#pragma unroll
            for (int i = 0; i < 8; ++i) {
                const floatx4 a = acc[i * 2 + j];
                ushort4 v;
                v.x = f2bf(a[0] + bb); v.y = f2bf(a[1] + bb);
                v.z = f2bf(a[2] + bb); v.w = f2bf(a[3] + bb);
                *(ushort4*)(orow + sbase + i * 16 + quad * 4) = v;
            }
        }
    } else {
        // Q/K: m-row per lane, 4 consecutive hd per reg; 32B contiguous/instr.
#pragma unroll
        for (int i = 0; i < 2; ++i) {
            const int m = bm + wave * 32 + i * 16 + lm;
            const int b = m >> 11, s = m & 2047;
#pragma unroll
            for (int j = 0; j < 8; ++j) {
                const int nl = j * 16 + quad * 4;
                const int n = bn + nl;
                const int h = n >> 6, hd = n & 63;
                const floatx4 a = acc[i * 8 + j];
                ushort4 v;
                v.x = f2bf(a[0] + bias_s[nl + 0]);
                v.y = f2bf(a[1] + bias_s[nl + 1]);
                v.z = f2bf(a[2] + bias_s[nl + 2]);
                v.w = f2bf(a[3] + bias_s[nl + 3]);
                *(ushort4*)(out + (((size_t)(b * HH + h) * SS) + s) * HDD + hd) = v;
            }
        }
    }
}

// ---------------- proj GEMM: 64x128, full-line f32 stores ------------------
// Wave owns 16 m-rows, full n=128 (j 0..7). Lane: m = bm+wave*16+lm,
// n = bn+j*16+quad*4+r. float4 store x 4 quads = full 64B line.
__global__ __launch_bounds__(256) void gemm_proj_wa(
    const ushort* __restrict__ A, const ushort* __restrict__ W,
    const float* __restrict__ bias, float* __restrict__ out)
{
    __shared__ ushort As[64 * 32];
    __shared__ ushort Bs[128 * 32];
    __shared__ float bias_s[128];

    const int tid = threadIdx.x;
    const int bm = blockIdx.x * 64, bn = blockIdx.y * 128;
    const int wave = tid >> 6, lane = tid & 63, quad = lane >> 4, lm = lane & 15;
    const int r0 = tid >> 2, c0 = (tid & 3) * 8;

    if (tid < 128) bias_s[tid] = bias[bn + tid];

    const floatx4 zz = {0.f, 0.f, 0.f, 0.f};
    floatx4 acc[8];
#pragma unroll
    for (int j = 0; j < 8; ++j) acc[j] = zz;

    for (int k0 = 0; k0 < DD; k0 += 32) {
        __syncthreads();
        dma16(&As[r0 * 32 + c0], A + (size_t)(bm + (r0 & 63)) * DD + k0 + c0);
        dma16(&Bs[r0 * 32 + c0], W + (size_t)(bn + r0) * DD + k0 + c0);
        dma16(&Bs[(64 + r0) * 32 + c0], W + (size_t)(bn + 64 + r0) * DD + k0 + c0);
        __syncthreads();

        const short8 af = *(const short8*)&As[(wave * 16 + lm) * 32 + quad * 8];
#pragma unroll
        for (int j = 0; j < 8; ++j) {
            const short8 bf = *(const short8*)&Bs[(j * 16 + lm) * 32 + quad * 8];
            acc[j] = __builtin_amdgcn_mfma_f32_16x16x32_bf16(bf, af, acc[j], 0, 0, 0);
        }
    }

    const int m = bm + wave * 16 + lm;
#pragma unroll
    for (int j = 0; j < 8; ++j) {
        const int nl = j * 16 + quad * 4;
        float4 v;
        v.x = acc[j][0] + bias_s[nl + 0];
        v.y = acc[j][1] + bias_s[nl + 1];
        v.z = acc[j][2] + bias_s[nl + 2];
        v.w = acc[j][3] + bias_s[nl + 3];
        *(float4*)(out + (size_t)m * DD + bn + nl) = v;
    }
}

// ---------------- Attention: swapped MFMA, split-K x2 (R10) ----------------
// Q,K: (B*H,S,HD) bf16 (Q pre-scaled by QSCL -> logits are log2-domain).
// Vt: (B*H,HD,S) bf16.
// Opart: 2 x (B,S,D) bf16 unnormalized. lbuf: 2 x (B*H*S) f32.
__global__ __launch_bounds__(256) void attn_mfma(
    const ushort* __restrict__ Q, const ushort* __restrict__ K,
    const ushort* __restrict__ Vt, const int* __restrict__ am,
    ushort* __restrict__ Opart, float* __restrict__ lbuf)
{
    __shared__ ushort Ks[64 * 72];
    __shared__ ushort Vts[64 * 72];
    __shared__ ushort Ps[4][32 * 72];
    __shared__ int amk_s[64];

    const int tid = threadIdx.x;
    const int wq = tid >> 6, lane = tid & 63, quad = lane >> 4, lm = lane & 15;
    const int bh = blockIdx.y, b = bh >> 4, h = bh & 15;
    // Balance: same-CU blocks are {same x, both b, both splits}. qt = b?x:15-x
    // pairs workloads (x+1)+(16-x)=17 tiles/split on every CU.
    const int qt = b ? (int)blockIdx.x : (int)(gridDim.x - 1 - blockIdx.x);
    const int split = blockIdx.z;
    const size_t base = (size_t)bh * SS * HDD;
    const size_t tbase = (size_t)bh * HDD * SS;
    const int* amrow = am + b * SS;
    const int q0 = qt * 128 + wq * 32;

    short8 qf[2][2];
#pragma unroll
    for (int sub = 0; sub < 2; ++sub) {
        const ushort* qp = Q + base + (size_t)(q0 + sub * 16 + lm) * HDD + quad * 8;
        qf[sub][0] = *(const short8*)qp;
        qf[sub][1] = *(const short8*)(qp + 32);
    }
    int amq[2];
#pragma unroll
    for (int sub = 0; sub < 2; ++sub) amq[sub] = amrow[q0 + sub * 16 + lm];
    const bool allq = __all(amq[0] != 0 && amq[1] != 0);

    const floatx4 zz = {0.f, 0.f, 0.f, 0.f};
    floatx4 o_acc[2][4];
#pragma unroll
    for (int sub = 0; sub < 2; ++sub)
#pragma unroll
        for (int n2 = 0; n2 < 4; ++n2) o_acc[sub][n2] = zz;
    float l_lane[2] = {0.f, 0.f};

    const int sr = tid >> 2, sc = (tid & 3) * 16;
    const int ktmax = 2 * qt + 1;

    // ---- prologue: stage first tile ----
    uint4 kra, krb, vra, vrb;
    int amr = 1;
    {
        const ushort* kp = K + base + (size_t)(split * 64 + sr) * HDD + sc;
        kra = ((const uint4*)kp)[0]; krb = ((const uint4*)kp)[1];
        const ushort* vp = Vt + tbase + (size_t)sr * SS + split * 64 + sc;
        vra = ((const uint4*)vp)[0]; vrb = ((const uint4*)vp)[1];
        if (tid < 64) amr = amrow[split * 64 + tid];
    }
    *(uint4*)&Ks[sr * 72 + sc] = kra;
    *(uint4*)&Ks[sr * 72 + sc + 8] = krb;
    *(uint4*)&Vts[sr * 72 + sc] = vra;
    *(uint4*)&Vts[sr * 72 + sc + 8] = vrb;
    if (tid < 64) amk_s[tid] = amr;
    __syncthreads();

    for (int kt = split; kt <= ktmax; kt += 2) {
        const int nxt = kt + 2;
        const bool have_nxt = nxt <= ktmax;
        // T14: issue next tile's global loads now; LDS writes after barrier.
        if (have_nxt) {
            const ushort* kp = K + base + (size_t)(nxt * 64 + sr) * HDD + sc;
            kra = ((const uint4*)kp)[0]; krb = ((const uint4*)kp)[1];
            const ushort* vp = Vt + tbase + (size_t)sr * SS + nxt * 64 + sc;
            vra = ((const uint4*)vp)[0]; vrb = ((const uint4*)vp)[1];
            if (tid < 64) amr = amrow[nxt * 64 + tid];
        }

        // ---- S^T = K Q^T (swapped): regs = 4 consecutive t ----
        const bool allk = (__ballot(amk_s[lane] != 0) == ~0ull);
        const bool fast = allk & allq & ((kt * 64 + 63) <= q0);
        if (fast) {
#pragma unroll
            for (int nt = 0; nt < 4; ++nt) {
                const short8 kf0 = *(const short8*)&Ks[(nt * 16 + lm) * 72 + quad * 8];
                const short8 kf1 = *(const short8*)&Ks[(nt * 16 + lm) * 72 + 32 + quad * 8];
#pragma unroll
                for (int sub = 0; sub < 2; ++sub) {
                    floatx4 s = zz;
                    s = __builtin_amdgcn_mfma_f32_16x16x32_bf16(kf0, qf[sub][0], s, 0, 0, 0);
                    s = __builtin_amdgcn_mfma_f32_16x16x32_bf16(kf1, qf[sub][1], s, 0, 0, 0);
                    const float e0 = exp2f(fminf(s[0], 40.f));
                    const float e1 = exp2f(fminf(s[1], 40.f));
                    const float e2 = exp2f(fminf(s[2], 40.f));
                    const float e3 = exp2f(fminf(s[3], 40.f));
                    l_lane[sub] += (e0 + e1) + (e2 + e3);
                    uint2 pv;
                    pv.x = cvtpk(e0, e1); pv.y = cvtpk(e2, e3);
                    *(uint2*)&Ps[wq][(sub * 16 + lm) * 72 + nt * 16 + quad * 4] = pv;
                }
            }
        } else {
#pragma unroll
            for (int nt = 0; nt < 4; ++nt) {
                const short8 kf0 = *(const short8*)&Ks[(nt * 16 + lm) * 72 + quad * 8];
                const short8 kf1 = *(const short8*)&Ks[(nt * 16 + lm) * 72 + 32 + quad * 8];
                const int4 amk4 = *(const int4*)&amk_s[nt * 16 + quad * 4];
#pragma unroll
                for (int sub = 0; sub < 2; ++sub) {
                    floatx4 s = zz;
                    s = __builtin_amdgcn_mfma_f32_16x16x32_bf16(kf0, qf[sub][0], s, 0, 0, 0);
                    s = __builtin_amdgcn_mfma_f32_16x16x32_bf16(kf1, qf[sub][1], s, 0, 0, 0);
                    const int qg = q0 + sub * 16 + lm;
                    const int t0 = kt * 64 + nt * 16 + quad * 4;
                    const bool mq = amq[sub] != 0;
                    const bool ok0 = amk4.x && mq && (t0 + 0 <= qg);
                    const bool ok1 = amk4.y && mq && (t0 + 1 <= qg);
                    const bool ok2 = amk4.z && mq && (t0 + 2 <= qg);
                    const bool ok3 = amk4.w && mq && (t0 + 3 <= qg);
                    const float e0 = exp2f(fminf(ok0 ? s[0] : NEG_BIG, 40.f));
                    const float e1 = exp2f(fminf(ok1 ? s[1] : NEG_BIG, 40.f));
                    const float e2 = exp2f(fminf(ok2 ? s[2] : NEG_BIG, 40.f));
                    const float e3 = exp2f(fminf(ok3 ? s[3] : NEG_BIG, 40.f));
                    l_lane[sub] += (e0 + e1) + (e2 + e3);
                    uint2 pv;
                    pv.x = cvtpk(e0, e1); pv.y = cvtpk(e2, e3);
                    *(uint2*)&Ps[wq][(sub * 16 + lm) * 72 + nt * 16 + quad * 4] = pv;
                }
            }
        }

        // ---- O^T += V^T P^T (swapped): regs = 4 consecutive hd ----
        short8 af[2][2];
#pragma unroll
        for (int sub = 0; sub < 2; ++sub) {
            af[sub][0] = *(const short8*)&Ps[wq][(sub * 16 + lm) * 72 + quad * 8];
            af[sub][1] = *(const short8*)&Ps[wq][(sub * 16 + lm) * 72 + 32 + quad * 8];
        }
#pragma unroll
        for (int n2 = 0; n2 < 4; ++n2) {
            const short8 vf0 = *(const short8*)&Vts[(n2 * 16 + lm) * 72 + quad * 8];
            const short8 vf1 = *(const short8*)&Vts[(n2 * 16 + lm) * 72 + 32 + quad * 8];
#pragma unroll
            for (int sub = 0; sub < 2; ++sub) {
                o_acc[sub][n2] = __builtin_amdgcn_mfma_f32_16x16x32_bf16(
                    vf0, af[sub][0], o_acc[sub][n2], 0, 0, 0);
                o_acc[sub][n2] = __builtin_amdgcn_mfma_f32_16x16x32_bf16(
                    vf1, af[sub][1], o_acc[sub][n2], 0, 0, 0);
            }
        }

        if (have_nxt) {
            __syncthreads();  // all waves done reading Ks/Vts/amk_s
            *(uint4*)&Ks[sr * 72 + sc] = kra;
            *(uint4*)&Ks[sr * 72 + sc + 8] = krb;
            *(uint4*)&Vts[sr * 72 + sc] = vra;
            *(uint4*)&Vts[sr * 72 + sc + 8] = vrb;
            if (tid < 64) amk_s[tid] = amr;
            __syncthreads();  // next tile ready
        }
    }

    // ---- l: sum across quads (lane's l covers its t-subset; q = lm) ----
#pragma unroll
    for (int sub = 0; sub < 2; ++sub) {
        float l = l_lane[sub];
        l += __shfl_xor(l, 16);
        l += __shfl_xor(l, 32);
        if (quad == 0)
            lbuf[(size_t)split * (BB * HH * SS) + (size_t)bh * SS + q0 + sub * 16 + lm] = l;
        // ---- epilogue: unnormalized O, packed 4 consecutive hd ----
        const int srow = q0 + sub * 16 + lm;
#pragma unroll
        for (int n2 = 0; n2 < 4; ++n2) {
            uint2 v;
            v.x = cvtpk(o_acc[sub][n2][0], o_acc[sub][n2][1]);
            v.y = cvtpk(o_acc[sub][n2][2], o_acc[sub][n2][3]);
            *(uint2*)(Opart + (size_t)split * (BB * SS * DD)
                        + ((size_t)(b * SS + srow)) * DD + h * HDD + n2 * 16 + quad * 4) = v;
        }
    }
}

// ---------------- combine: A = (O0 + O1) / (l0 + l1), bf16 ----------------
__global__ __launch_bounds__(256) void combine(
    const ushort* __restrict__ Opart, const float* __restrict__ lbuf,
    ushort* __restrict__ Aout)
{
    const size_t e = ((size_t)blockIdx.x * 256 + threadIdx.x) * 8;
    const int m = (int)(e >> 10);
    const int col = (int)(e & 1023);
    const int b = m >> 11, s = m & 2047, h = col >> 6;
    const float l = lbuf[(b * HH + h) * SS + s]
                  + lbuf[BB * HH * SS + (b * HH + h) * SS + s];
    const float inv = l > 0.f ? 1.f / l : 0.f;
    const uint4 u0 = *(const uint4*)(Opart + e);
    const uint4 u1 = *(const uint4*)(Opart + (size_t)BB * SS * DD + e);
    float f0[8], f1[8];
    unpack8(u0, f0);
    unpack8(u1, f1);
    uint4 o;
    o.x = pk2((f0[0] + f1[0]) * inv, (f0[1] + f1[1]) * inv);
    o.y = pk2((f0[2] + f1[2]) * inv, (f0[3] + f1[3]) * inv);
    o.z = pk2((f0[4] + f1[4]) * inv, (f0[5] + f1[5]) * inv);
    o.w = pk2((f0[6] + f1[6]) * inv, (f0[7] + f1[7]) * inv);
    *(uint4*)(Aout + e) = o;
}

extern "C" void kernel_launch(void* const* d_in, const int* in_sizes, int n_in,
                              void* d_out, int out_size, void* d_ws, size_t ws_size,
                              hipStream_t stream) {
    const float* x  = (const float*)d_in[0];
    const int*   am = (const int*)d_in[1];
    const float* Wq = (const float*)d_in[2];
    const float* bq = (const float*)d_in[3];
    const float* Wk = (const float*)d_in[4];
    const float* bk = (const float*)d_in[5];
    const float* Wv = (const float*)d_in[6];
    const float* bv = (const float*)d_in[7];
    const float* Wp = (const float*)d_in[8];
    const float* bp = (const float*)d_in[9];
    float* out = (float*)d_out;

    const size_t elems = (size_t)BB * HH * SS * HDD;  // 4M
    ushort* q_ws = (ushort*)d_ws;                 // Q; later combined A
    ushort* k_ws = q_ws + elems;
    ushort* v_ws = k_ws + elems;                  // V^T (B,H,HD,S)
    float*  lbuf = (float*)(v_ws + elems);        // 2 x 256 KB in a_ws slot
    ushort* wpb  = (ushort*)(lbuf + 2 * BB * HH * SS);  // bf16 Wp (2 MB)

    // d_out scratch: bf16 x (4M) + Wq/Wk/Wv (1M each); later attn partials
    ushort* xb  = (ushort*)d_out;
    ushort* wqb = xb + 4194304;
    ushort* wkb = wqb + 1048576;
    ushort* wvb = wkb + 1048576;

    cvt_all<<<4096, 256, 0, stream>>>(x, Wq, Wk, Wv, Wp, xb, wpb);

    gemm_qkv_wa<<<dim3(32, 8, 3), 256, 0, stream>>>(
        xb, wqb, wkb, wvb, bq, bk, bv, q_ws, k_ws, v_ws);

    attn_mfma<<<dim3(SS / 128, BB * HH, 2), 256, 0, stream>>>(
        q_ws, k_ws, v_ws, am, (ushort*)d_out, lbuf);

    combine<<<2048, 256, 0, stream>>>((const ushort*)d_out, lbuf, q_ws);

    gemm_proj_wa<<<dim3(64, 8), 256, 0, stream>>>(q_ws, wpb, bp, out);
}

// Round 10
// 219.683 us; speedup vs baseline: 1.5256x; 1.0601x over previous
//
#include <hip/hip_runtime.h>

// MHA forward: B=2, S=2048, D=1024, H=16, HD=64. Inputs f32, mask int32,
// OUTPUT f32. Intermediates bf16.
//
// Round 18: assemble best-measured pieces.
//  - QKV: R17's gemm_qkv_wa (64.7us measured; WRITE fixed at 24MB logical)
//    + running-pointer dma16 addressing (cut the per-step addr recompute
//    that shows as 24% VALUBusy).
//  - proj: back to R13's reg-staged 128x128 pipeline (proven ~45-48us;
//    f32 quad stores are already full 64B lines) -- R17's 64x128 dma16
//    variant had half the MFMA/staging amortization and regressed (~60us).
//  - attn_mfma (R10, 58.3us) / cvt_all / combine unchanged.

#define BB 2
#define SS 2048
#define DD 1024
#define HH 16
#define HDD 64
#define NEG_BIG (-1.0e30f)
#define QSCL 0.18033688011112042f  // 0.125 * log2(e)

typedef __attribute__((ext_vector_type(8))) short short8;
typedef __attribute__((ext_vector_type(4))) float floatx4;
typedef unsigned int u32;
#define AS_GLOBAL __attribute__((address_space(1)))
#define AS_LDS    __attribute__((address_space(3)))

__device__ __forceinline__ ushort f2bf(float f) {  // RNE
    unsigned u = __float_as_uint(f);
    u += 0x7fffu + ((u >> 16) & 1u);
    return (ushort)(u >> 16);
}
__device__ __forceinline__ unsigned pk2(float a, float b) {
    return ((unsigned)f2bf(b) << 16) | (unsigned)f2bf(a);
}
__device__ __forceinline__ unsigned cvtpk(float a, float b) {  // lo=a, hi=b, RNE
    unsigned r;
    asm("v_cvt_pk_bf16_f32 %0, %1, %2" : "=v"(r) : "v"(a), "v"(b));
    return r;
}
__device__ __forceinline__ void unpack8(const uint4 u, float* d) {
    d[0] = __uint_as_float(u.x << 16);
    d[1] = __uint_as_float(u.x & 0xffff0000u);
    d[2] = __uint_as_float(u.y << 16);
    d[3] = __uint_as_float(u.y & 0xffff0000u);
    d[4] = __uint_as_float(u.z << 16);
    d[5] = __uint_as_float(u.z & 0xffff0000u);
    d[6] = __uint_as_float(u.w << 16);
    d[7] = __uint_as_float(u.w & 0xffff0000u);
}
__device__ __forceinline__ void dma16(void* lds, const void* g) {
    __builtin_amdgcn_global_load_lds((const AS_GLOBAL u32*)g, (AS_LDS u32*)lds,
                                     16, 0, 0);
}

// ---------------- f32 -> bf16 conversion (x, Wq, Wk, Wv, Wp) ----------------
// Wq is pre-scaled by QSCL (attention scale + log2e folded into Q).
__global__ __launch_bounds__(256) void cvt_all(
    const float* __restrict__ x, const float* __restrict__ wq,
    const float* __restrict__ wk, const float* __restrict__ wv,
    const float* __restrict__ wp,
    ushort* __restrict__ dst, ushort* __restrict__ wp_dst)
{
    const size_t flat = ((size_t)blockIdx.x * 256 + threadIdx.x) * 8;
    const float* s;
    ushort* d = dst + flat;
    size_t off;
    float scl = 1.0f;
    if (flat < (size_t)4194304)      { s = x;  off = flat; }
    else if (flat < (size_t)5242880) { s = wq; off = flat - 4194304; scl = QSCL; }
    else if (flat < (size_t)6291456) { s = wk; off = flat - 5242880; }
    else if (flat < (size_t)7340032) { s = wv; off = flat - 6291456; }
    else { s = wp; off = flat - 7340032; d = wp_dst + off; }
    const float4 a = ((const float4*)(s + off))[0];
    const float4 b = ((const float4*)(s + off))[1];
    uint4 u;
    u.x = pk2(a.x * scl, a.y * scl); u.y = pk2(a.z * scl, a.w * scl);
    u.z = pk2(b.x * scl, b.y * scl); u.w = pk2(b.z * scl, b.w * scl);
    *(uint4*)d = u;
}

// ---------------- QKV GEMM: m97-style staging, line-friendly epilogue ------
// z=0: Q (swapped, bias*QSCL, out (B,H,S,HD))
// z=1: K (swapped, out (B,H,S,HD))
// z=2: V (unswapped, out (B,H,HD,S))
__global__ __launch_bounds__(256) void gemm_qkv_wa(
    const ushort* __restrict__ A,
    const ushort* __restrict__ W0, const ushort* __restrict__ W1,
    const ushort* __restrict__ W2,
    const float* __restrict__ B0, const float* __restrict__ B1,
    const float* __restrict__ B2,
    ushort* __restrict__ O0, ushort* __restrict__ O1, ushort* __restrict__ O2)
{
    __shared__ ushort As[128 * 32];
    __shared__ ushort Bs[128 * 32];
    __shared__ float bias_s[128];

    const int z = blockIdx.z;
    const ushort* W = (z == 0) ? W0 : (z == 1 ? W1 : W2);
    const float* bias = (z == 0) ? B0 : (z == 1 ? B1 : B2);
    ushort* out = (z == 0) ? O0 : (z == 1 ? O1 : O2);
    const bool isv = (z == 2);

    const int tid = threadIdx.x;
    const int bm = blockIdx.x * 128, bn = blockIdx.y * 128;
    const int wave = tid >> 6, lane = tid & 63, quad = lane >> 4, lm = lane & 15;
    const int r0 = tid >> 2, c0 = (tid & 3) * 8;

    if (tid < 128) {
        float bb = bias[bn + tid];
        if (z == 0) bb *= QSCL;
        bias_s[tid] = bb;
    }

    const floatx4 zz = {0.f, 0.f, 0.f, 0.f};
    floatx4 acc[16];
#pragma unroll
    for (int i = 0; i < 16; ++i) acc[i] = zz;

    // running pointers: strength-reduced dma16 addressing (+32/step)
    const ushort* a0 = A + (size_t)(bm + r0) * DD + c0;
    const ushort* a1 = A + (size_t)(bm + 64 + r0) * DD + c0;
    const ushort* w0 = W + (size_t)(bn + r0) * DD + c0;
    const ushort* w1 = W + (size_t)(bn + 64 + r0) * DD + c0;
    ushort* const lA0 = &As[r0 * 32 + c0];
    ushort* const lA1 = &As[(64 + r0) * 32 + c0];
    ushort* const lB0 = &Bs[r0 * 32 + c0];
    ushort* const lB1 = &Bs[(64 + r0) * 32 + c0];

    for (int k0 = 0; k0 < DD; k0 += 32) {
        __syncthreads();
        dma16(lA0, a0); dma16(lA1, a1);
        dma16(lB0, w0); dma16(lB1, w1);
        a0 += 32; a1 += 32; w0 += 32; w1 += 32;
        __syncthreads();

        if (isv) {
            const short8 bf0 = *(const short8*)&Bs[(wave * 32 + lm) * 32 + quad * 8];
            const short8 bf1 = *(const short8*)&Bs[(wave * 32 + 16 + lm) * 32 + quad * 8];
#pragma unroll
            for (int i = 0; i < 8; ++i) {
                const short8 af = *(const short8*)&As[(i * 16 + lm) * 32 + quad * 8];
                acc[i * 2 + 0] = __builtin_amdgcn_mfma_f32_16x16x32_bf16(
                    af, bf0, acc[i * 2 + 0], 0, 0, 0);
                acc[i * 2 + 1] = __builtin_amdgcn_mfma_f32_16x16x32_bf16(
                    af, bf1, acc[i * 2 + 1], 0, 0, 0);
            }
        } else {
            const short8 af0 = *(const short8*)&As[(wave * 32 + lm) * 32 + quad * 8];
            const short8 af1 = *(const short8*)&As[(wave * 32 + 16 + lm) * 32 + quad * 8];
#pragma unroll
            for (int j = 0; j < 8; ++j) {
                const short8 bf = *(const short8*)&Bs[(j * 16 + lm) * 32 + quad * 8];
                acc[j] = __builtin_amdgcn_mfma_f32_16x16x32_bf16(
                    bf, af0, acc[j], 0, 0, 0);
                acc[8 + j] = __builtin_amdgcn_mfma_f32_16x16x32_bf16(
                    bf, af1, acc[8 + j], 0, 0, 0);
            }
        }
    }

    if (isv) {
        // V: n-row per lane, 4 consecutive s per reg; 32B contiguous/instr.
        const int b = bm >> 11, sbase = bm & 2047;
#pragma unroll
        for (int j = 0; j < 2; ++j) {
            const int n = bn + wave * 32 + j * 16 + lm;
            const float bb = bias_s[n - bn];
            ushort* orow = out + ((size_t)(b * DD + n)) * SS;
#pragma unroll
            for (int i = 0; i < 8; ++i) {
                const floatx4 a = acc[i * 2 + j];
                ushort4 v;
                v.x = f2bf(a[0] + bb); v.y = f2bf(a[1] + bb);
                v.z = f2bf(a[2] + bb); v.w = f2bf(a[3] + bb);
                *(ushort4*)(orow + sbase + i * 16 + quad * 4) = v;
            }
        }
    } else {
        // Q/K: m-row per lane, 4 consecutive hd per reg; 32B contiguous/instr.
#pragma unroll
        for (int i = 0; i < 2; ++i) {
            const int m = bm + wave * 32 + i * 16 + lm;
            const int b = m >> 11, s = m & 2047;
#pragma unroll
            for (int j = 0; j < 8; ++j) {
                const int nl = j * 16 + quad * 4;
                const int n = bn + nl;
                const int h = n >> 6, hd = n & 63;
                const floatx4 a = acc[i * 8 + j];
                ushort4 v;
                v.x = f2bf(a[0] + bias_s[nl + 0]);
                v.y = f2bf(a[1] + bias_s[nl + 1]);
                v.z = f2bf(a[2] + bias_s[nl + 2]);
                v.w = f2bf(a[3] + bias_s[nl + 3]);
                *(ushort4*)(out + (((size_t)(b * HH + h) * SS) + s) * HDD + hd) = v;
            }
        }
    }
}

// ---------------- proj GEMM: 128x128, reg-staged pipeline (R13), f32 out ---
// swapped MFMA: regs = 4 consecutive n; quads give full 64B-line stores.
__global__ __launch_bounds__(256, 2) void gemm_proj_rs(
    const ushort* __restrict__ A, const ushort* __restrict__ W,
    const float* __restrict__ bias, float* __restrict__ out)
{
    __shared__ ushort As[128 * 32];
    __shared__ ushort Bs[128 * 32];
    __shared__ float bias_s[128];

    const int tid = threadIdx.x;
    const int bm = blockIdx.x * 128, bn = blockIdx.y * 128;
    const int wave = tid >> 6, lane = tid & 63, quad = lane >> 4, lm = lane & 15;
    const int wm = wave >> 1, wn = wave & 1;
    const int r0 = tid >> 2, c0 = (tid & 3) * 8;

    if (tid < 128) bias_s[tid] = bias[bn + tid];

    const floatx4 zz = {0.f, 0.f, 0.f, 0.f};
    floatx4 acc[4][4];
#pragma unroll
    for (int i = 0; i < 4; ++i)
#pragma unroll
        for (int j = 0; j < 4; ++j) acc[i][j] = zz;

    const ushort* ap = A + (size_t)(bm + r0) * DD + c0;
    const ushort* wpp = W + (size_t)(bn + r0) * DD + c0;

    uint4 ar0, ar1, wr0, wr1;
#define LOADT(K0)                                                \
    do {                                                         \
        ar0 = *(const uint4*)(ap + (K0));                        \
        ar1 = *(const uint4*)(ap + (size_t)64 * DD + (K0));      \
        wr0 = *(const uint4*)(wpp + (K0));                       \
        wr1 = *(const uint4*)(wpp + (size_t)64 * DD + (K0));     \
    } while (0)
#define STORET()                                                 \
    do {                                                         \
        *(uint4*)&As[r0 * 32 + c0] = ar0;                        \
        *(uint4*)&As[(64 + r0) * 32 + c0] = ar1;                 \
        *(uint4*)&Bs[r0 * 32 + c0] = wr0;                        \
        *(uint4*)&Bs[(64 + r0) * 32 + c0] = wr1;                 \
    } while (0)

    LOADT(0);
    STORET();
    __syncthreads();

    for (int k0 = 0; k0 < DD; k0 += 32) {
        const bool have_nxt = (k0 + 32) < DD;
        if (have_nxt) LOADT(k0 + 32);  // prefetch: latency hides under MFMA

        short8 af[4], bf[4];
#pragma unroll
        for (int i = 0; i < 4; ++i)
            af[i] = *(const short8*)&As[(wm * 64 + i * 16 + lm) * 32 + quad * 8];
#pragma unroll
        for (int j = 0; j < 4; ++j)
            bf[j] = *(const short8*)&Bs[(wn * 64 + j * 16 + lm) * 32 + quad * 8];
#pragma unroll
        for (int i = 0; i < 4; ++i)
#pragma unroll
            for (int j = 0; j < 4; ++j)
                acc[i][j] = __builtin_amdgcn_mfma_f32_16x16x32_bf16(
                    bf[j], af[i], acc[i][j], 0, 0, 0);

        if (have_nxt) {
            __syncthreads();
            STORET();
            __syncthreads();
        }
    }
#undef LOADT
#undef STORET

#pragma unroll
    for (int i = 0; i < 4; ++i) {
#pragma unroll
        for (int j = 0; j < 4; ++j) {
            const int nl = wn * 64 + j * 16 + quad * 4;
            const int n = bn + nl;
            const int m = bm + wm * 64 + i * 16 + lm;
            float4 v;
            v.x = acc[i][j][0] + bias_s[nl + 0];
            v.y = acc[i][j][1] + bias_s[nl + 1];
            v.z = acc[i][j][2] + bias_s[nl + 2];
            v.w = acc[i][j][3] + bias_s[nl + 3];
            *(float4*)(out + (size_t)m * DD + n) = v;
        }
    }
}

// ---------------- Attention: swapped MFMA, split-K x2 (R10) ----------------
// Q,K: (B*H,S,HD) bf16 (Q pre-scaled by QSCL -> logits are log2-domain).
// Vt: (B*H,HD,S) bf16.
// Opart: 2 x (B,S,D) bf16 unnormalized. lbuf: 2 x (B*H*S) f32.
__global__ __launch_bounds__(256) void attn_mfma(
    const ushort* __restrict__ Q, const ushort* __restrict__ K,
    const ushort* __restrict__ Vt, const int* __restrict__ am,
    ushort* __restrict__ Opart, float* __restrict__ lbuf)
{
    __shared__ ushort Ks[64 * 72];
    __shared__ ushort Vts[64 * 72];
    __shared__ ushort Ps[4][32 * 72];
    __shared__ int amk_s[64];

    const int tid = threadIdx.x;
    const int wq = tid >> 6, lane = tid & 63, quad = lane >> 4, lm = lane & 15;
    const int bh = blockIdx.y, b = bh >> 4, h = bh & 15;
    // Balance: same-CU blocks are {same x, both b, both splits}. qt = b?x:15-x
    // pairs workloads (x+1)+(16-x)=17 tiles/split on every CU.
    const int qt = b ? (int)blockIdx.x : (int)(gridDim.x - 1 - blockIdx.x);
    const int split = blockIdx.z;
    const size_t base = (size_t)bh * SS * HDD;
    const size_t tbase = (size_t)bh * HDD * SS;
    const int* amrow = am + b * SS;
    const int q0 = qt * 128 + wq * 32;

    short8 qf[2][2];
#pragma unroll
    for (int sub = 0; sub < 2; ++sub) {
        const ushort* qp = Q + base + (size_t)(q0 + sub * 16 + lm) * HDD + quad * 8;
        qf[sub][0] = *(const short8*)qp;
        qf[sub][1] = *(const short8*)(qp + 32);
    }
    int amq[2];
#pragma unroll
    for (int sub = 0; sub < 2; ++sub) amq[sub] = amrow[q0 + sub * 16 + lm];
    const bool allq = __all(amq[0] != 0 && amq[1] != 0);

    const floatx4 zz = {0.f, 0.f, 0.f, 0.f};
    floatx4 o_acc[2][4];
#pragma unroll
    for (int sub = 0; sub < 2; ++sub)
#pragma unroll
        for (int n2 = 0; n2 < 4; ++n2) o_acc[sub][n2] = zz;
    float l_lane[2] = {0.f, 0.f};

    const int sr = tid >> 2, sc = (tid & 3) * 16;
    const int ktmax = 2 * qt + 1;

    // ---- prologue: stage first tile ----
    uint4 kra, krb, vra, vrb;
    int amr = 1;
    {
        const ushort* kp = K + base + (size_t)(split * 64 + sr) * HDD + sc;
        kra = ((const uint4*)kp)[0]; krb = ((const uint4*)kp)[1];
        const ushort* vp = Vt + tbase + (size_t)sr * SS + split * 64 + sc;
        vra = ((const uint4*)vp)[0]; vrb = ((const uint4*)vp)[1];
        if (tid < 64) amr = amrow[split * 64 + tid];
    }
    *(uint4*)&Ks[sr * 72 + sc] = kra;
    *(uint4*)&Ks[sr * 72 + sc + 8] = krb;
    *(uint4*)&Vts[sr * 72 + sc] = vra;
    *(uint4*)&Vts[sr * 72 + sc + 8] = vrb;
    if (tid < 64) amk_s[tid] = amr;
    __syncthreads();

    for (int kt = split; kt <= ktmax; kt += 2) {
        const int nxt = kt + 2;
        const bool have_nxt = nxt <= ktmax;
        // T14: issue next tile's global loads now; LDS writes after barrier.
        if (have_nxt) {
            const ushort* kp = K + base + (size_t)(nxt * 64 + sr) * HDD + sc;
            kra = ((const uint4*)kp)[0]; krb = ((const uint4*)kp)[1];
            const ushort* vp = Vt + tbase + (size_t)sr * SS + nxt * 64 + sc;
            vra = ((const uint4*)vp)[0]; vrb = ((const uint4*)vp)[1];
            if (tid < 64) amr = amrow[nxt * 64 + tid];
        }

        // ---- S^T = K Q^T (swapped): regs = 4 consecutive t ----
        const bool allk = (__ballot(amk_s[lane] != 0) == ~0ull);
        const bool fast = allk & allq & ((kt * 64 + 63) <= q0);
        if (fast) {
#pragma unroll
            for (int nt = 0; nt < 4; ++nt) {
                const short8 kf0 = *(const short8*)&Ks[(nt * 16 + lm) * 72 + quad * 8];
                const short8 kf1 = *(const short8*)&Ks[(nt * 16 + lm) * 72 + 32 + quad * 8];
#pragma unroll
                for (int sub = 0; sub < 2; ++sub) {
                    floatx4 s = zz;
                    s = __builtin_amdgcn_mfma_f32_16x16x32_bf16(kf0, qf[sub][0], s, 0, 0, 0);
                    s = __builtin_amdgcn_mfma_f32_16x16x32_bf16(kf1, qf[sub][1], s, 0, 0, 0);
                    const float e0 = exp2f(fminf(s[0], 40.f));
                    const float e1 = exp2f(fminf(s[1], 40.f));
                    const float e2 = exp2f(fminf(s[2], 40.f));
                    const float e3 = exp2f(fminf(s[3], 40.f));
                    l_lane[sub] += (e0 + e1) + (e2 + e3);
                    uint2 pv;
                    pv.x = cvtpk(e0, e1); pv.y = cvtpk(e2, e3);
                    *(uint2*)&Ps[wq][(sub * 16 + lm) * 72 + nt * 16 + quad * 4] = pv;
                }
            }
        } else {
#pragma unroll
            for (int nt = 0; nt < 4; ++nt) {
                const short8 kf0 = *(const short8*)&Ks[(nt * 16 + lm) * 72 + quad * 8];
                const short8 kf1 = *(const short8*)&Ks[(nt * 16 + lm) * 72 + 32 + quad * 8];
                const int4 amk4 = *(const int4*)&amk_s[nt * 16 + quad * 4];
#pragma unroll
                for (int sub = 0; sub < 2; ++sub) {
                    floatx4 s = zz;
                    s = __builtin_amdgcn_mfma_f32_16x16x32_bf16(kf0, qf[sub][0], s, 0, 0, 0);
                    s = __builtin_amdgcn_mfma_f32_16x16x32_bf16(kf1, qf[sub][1], s, 0, 0, 0);
                    const int qg = q0 + sub * 16 + lm;
                    const int t0 = kt * 64 + nt * 16 + quad * 4;
                    const bool mq = amq[sub] != 0;
                    const bool ok0 = amk4.x && mq && (t0 + 0 <= qg);
                    const bool ok1 = amk4.y && mq && (t0 + 1 <= qg);
                    const bool ok2 = amk4.z && mq && (t0 + 2 <= qg);
                    const bool ok3 = amk4.w && mq && (t0 + 3 <= qg);
                    const float e0 = exp2f(fminf(ok0 ? s[0] : NEG_BIG, 40.f));
                    const float e1 = exp2f(fminf(ok1 ? s[1] : NEG_BIG, 40.f));
                    const float e2 = exp2f(fminf(ok2 ? s[2] : NEG_BIG, 40.f));
                    const float e3 = exp2f(fminf(ok3 ? s[3] : NEG_BIG, 40.f));
                    l_lane[sub] += (e0 + e1) + (e2 + e3);
                    uint2 pv;
                    pv.x = cvtpk(e0, e1); pv.y = cvtpk(e2, e3);
                    *(uint2*)&Ps[wq][(sub * 16 + lm) * 72 + nt * 16 + quad * 4] = pv;
                }
            }
        }

        // ---- O^T += V^T P^T (swapped): regs = 4 consecutive hd ----
        short8 af[2][2];
#pragma unroll
        for (int sub = 0; sub < 2; ++sub) {
            af[sub][0] = *(const short8*)&Ps[wq][(sub * 16 + lm) * 72 + quad * 8];
            af[sub][1] = *(const short8*)&Ps[wq][(sub * 16 + lm) * 72 + 32 + quad * 8];
        }
#pragma unroll
        for (int n2 = 0; n2 < 4; ++n2) {
            const short8 vf0 = *(const short8*)&Vts[(n2 * 16 + lm) * 72 + quad * 8];
            const short8 vf1 = *(const short8*)&Vts[(n2 * 16 + lm) * 72 + 32 + quad * 8];
#pragma unroll
            for (int sub = 0; sub < 2; ++sub) {
                o_acc[sub][n2] = __builtin_amdgcn_mfma_f32_16x16x32_bf16(
                    vf0, af[sub][0], o_acc[sub][n2], 0, 0, 0);
                o_acc[sub][n2] = __builtin_amdgcn_mfma_f32_16x16x32_bf16(
                    vf1, af[sub][1], o_acc[sub][n2], 0, 0, 0);
            }
        }

        if (have_nxt) {
            __syncthreads();  // all waves done reading Ks/Vts/amk_s
            *(uint4*)&Ks[sr * 72 + sc] = kra;
            *(uint4*)&Ks[sr * 72 + sc + 8] = krb;
            *(uint4*)&Vts[sr * 72 + sc] = vra;
            *(uint4*)&Vts[sr * 72 + sc + 8] = vrb;
            if (tid < 64) amk_s[tid] = amr;
            __syncthreads();  // next tile ready
        }
    }

    // ---- l: sum across quads (lane's l covers its t-subset; q = lm) ----
#pragma unroll
    for (int sub = 0; sub < 2; ++sub) {
        float l = l_lane[sub];
        l += __shfl_xor(l, 16);
        l += __shfl_xor(l, 32);
        if (quad == 0)
            lbuf[(size_t)split * (BB * HH * SS) + (size_t)bh * SS + q0 + sub * 16 + lm] = l;
        // ---- epilogue: unnormalized O, packed 4 consecutive hd ----
        const int srow = q0 + sub * 16 + lm;
#pragma unroll
        for (int n2 = 0; n2 < 4; ++n2) {
            uint2 v;
            v.x = cvtpk(o_acc[sub][n2][0], o_acc[sub][n2][1]);
            v.y = cvtpk(o_acc[sub][n2][2], o_acc[sub][n2][3]);
            *(uint2*)(Opart + (size_t)split * (BB * SS * DD)
                        + ((size_t)(b * SS + srow)) * DD + h * HDD + n2 * 16 + quad * 4) = v;
        }
    }
}

// ---------------- combine: A = (O0 + O1) / (l0 + l1), bf16 ----------------
__global__ __launch_bounds__(256) void combine(
    const ushort* __restrict__ Opart, const float* __restrict__ lbuf,
    ushort* __restrict__ Aout)
{
    const size_t e = ((size_t)blockIdx.x * 256 + threadIdx.x) * 8;
    const int m = (int)(e >> 10);
    const int col = (int)(e & 1023);
    const int b = m >> 11, s = m & 2047, h = col >> 6;
    const float l = lbuf[(b * HH + h) * SS + s]
                  + lbuf[BB * HH * SS + (b * HH + h) * SS + s];
    const float inv = l > 0.f ? 1.f / l : 0.f;
    const uint4 u0 = *(const uint4*)(Opart + e);
    const uint4 u1 = *(const uint4*)(Opart + (size_t)BB * SS * DD + e);
    float f0[8], f1[8];
    unpack8(u0, f0);
    unpack8(u1, f1);
    uint4 o;
    o.x = pk2((f0[0] + f1[0]) * inv, (f0[1] + f1[1]) * inv);
    o.y = pk2((f0[2] + f1[2]) * inv, (f0[3] + f1[3]) * inv);
    o.z = pk2((f0[4] + f1[4]) * inv, (f0[5] + f1[5]) * inv);
    o.w = pk2((f0[6] + f1[6]) * inv, (f0[7] + f1[7]) * inv);
    *(uint4*)(Aout + e) = o;
}

extern "C" void kernel_launch(void* const* d_in, const int* in_sizes, int n_in,
                              void* d_out, int out_size, void* d_ws, size_t ws_size,
                              hipStream_t stream) {
    const float* x  = (const float*)d_in[0];
    const int*   am = (const int*)d_in[1];
    const float* Wq = (const float*)d_in[2];
    const float* bq = (const float*)d_in[3];
    const float* Wk = (const float*)d_in[4];
    const float* bk = (const float*)d_in[5];
    const float* Wv = (const float*)d_in[6];
    const float* bv = (const float*)d_in[7];
    const float* Wp = (const float*)d_in[8];
    const float* bp = (const float*)d_in[9];
    float* out = (float*)d_out;

    const size_t elems = (size_t)BB * HH * SS * HDD;  // 4M
    ushort* q_ws = (ushort*)d_ws;                 // Q; later combined A
    ushort* k_ws = q_ws + elems;
    ushort* v_ws = k_ws + elems;                  // V^T (B,H,HD,S)
    float*  lbuf = (float*)(v_ws + elems);        // 2 x 256 KB in a_ws slot
    ushort* wpb  = (ushort*)(lbuf + 2 * BB * HH * SS);  // bf16 Wp (2 MB)

    // d_out scratch: bf16 x (4M) + Wq/Wk/Wv (1M each); later attn partials
    ushort* xb  = (ushort*)d_out;
    ushort* wqb = xb + 4194304;
    ushort* wkb = wqb + 1048576;
    ushort* wvb = wkb + 1048576;

    cvt_all<<<4096, 256, 0, stream>>>(x, Wq, Wk, Wv, Wp, xb, wpb);

    gemm_qkv_wa<<<dim3(32, 8, 3), 256, 0, stream>>>(
        xb, wqb, wkb, wvb, bq, bk, bv, q_ws, k_ws, v_ws);

    attn_mfma<<<dim3(SS / 128, BB * HH, 2), 256, 0, stream>>>(
        q_ws, k_ws, v_ws, am, (ushort*)d_out, lbuf);

    combine<<<2048, 256, 0, stream>>>((const ushort*)d_out, lbuf, q_ws);

    gemm_proj_rs<<<dim3(32, 8), 256, 0, stream>>>(q_ws, wpb, bp, out);
}

// Round 11
// 218.080 us; speedup vs baseline: 1.5368x; 1.0074x over previous
//
#include <hip/hip_runtime.h>

// MHA forward: B=2, S=2048, D=1024, H=16, HD=64. Inputs f32, mask int32,
// OUTPUT f32. Intermediates bf16.
//
// Round 19: kill the measured 3.93M LDS bank conflicts in the GEMMs (T2).
//   Fragment reads As[(row)*32 + quad*8] are 8-way bank conflicts (bank =
//   16*(lm&1)+4*quad, 16 lanes on 2 spans). Fix: XOR chunk index with
//   (row>>1)&3 -> 2-way (free). With dma16 the LDS dest must stay linear
//   (rule 21), so qkv pre-swizzles the GLOBAL source chunk; proj (vector
//   stores) swizzles the LDS write directly. Reads use
//   csw8 = (quad ^ ((lm>>1)&3))*8 (row-base multiples of 16 cancel).
//  - Everything else identical to R18 (219.7us: attn 58.3 verified,
//    qkv_wa 64.7 measured, proj_rs reg-staged, cvt/combine unchanged).

#define BB 2
#define SS 2048
#define DD 1024
#define HH 16
#define HDD 64
#define NEG_BIG (-1.0e30f)
#define QSCL 0.18033688011112042f  // 0.125 * log2(e)

typedef __attribute__((ext_vector_type(8))) short short8;
typedef __attribute__((ext_vector_type(4))) float floatx4;
typedef unsigned int u32;
#define AS_GLOBAL __attribute__((address_space(1)))
#define AS_LDS    __attribute__((address_space(3)))

__device__ __forceinline__ ushort f2bf(float f) {  // RNE
    unsigned u = __float_as_uint(f);
    u += 0x7fffu + ((u >> 16) & 1u);
    return (ushort)(u >> 16);
}
__device__ __forceinline__ unsigned pk2(float a, float b) {
    return ((unsigned)f2bf(b) << 16) | (unsigned)f2bf(a);
}
__device__ __forceinline__ unsigned cvtpk(float a, float b) {  // lo=a, hi=b, RNE
    unsigned r;
    asm("v_cvt_pk_bf16_f32 %0, %1, %2" : "=v"(r) : "v"(a), "v"(b));
    return r;
}
__device__ __forceinline__ void unpack8(const uint4 u, float* d) {
    d[0] = __uint_as_float(u.x << 16);
    d[1] = __uint_as_float(u.x & 0xffff0000u);
    d[2] = __uint_as_float(u.y << 16);
    d[3] = __uint_as_float(u.y & 0xffff0000u);
    d[4] = __uint_as_float(u.z << 16);
    d[5] = __uint_as_float(u.z & 0xffff0000u);
    d[6] = __uint_as_float(u.w << 16);
    d[7] = __uint_as_float(u.w & 0xffff0000u);
}
__device__ __forceinline__ void dma16(void* lds, const void* g) {
    __builtin_amdgcn_global_load_lds((const AS_GLOBAL u32*)g, (AS_LDS u32*)lds,
                                     16, 0, 0);
}

// ---------------- f32 -> bf16 conversion (x, Wq, Wk, Wv, Wp) ----------------
// Wq is pre-scaled by QSCL (attention scale + log2e folded into Q).
__global__ __launch_bounds__(256) void cvt_all(
    const float* __restrict__ x, const float* __restrict__ wq,
    const float* __restrict__ wk, const float* __restrict__ wv,
    const float* __restrict__ wp,
    ushort* __restrict__ dst, ushort* __restrict__ wp_dst)
{
    const size_t flat = ((size_t)blockIdx.x * 256 + threadIdx.x) * 8;
    const float* s;
    ushort* d = dst + flat;
    size_t off;
    float scl = 1.0f;
    if (flat < (size_t)4194304)      { s = x;  off = flat; }
    else if (flat < (size_t)5242880) { s = wq; off = flat - 4194304; scl = QSCL; }
    else if (flat < (size_t)6291456) { s = wk; off = flat - 5242880; }
    else if (flat < (size_t)7340032) { s = wv; off = flat - 6291456; }
    else { s = wp; off = flat - 7340032; d = wp_dst + off; }
    const float4 a = ((const float4*)(s + off))[0];
    const float4 b = ((const float4*)(s + off))[1];
    uint4 u;
    u.x = pk2(a.x * scl, a.y * scl); u.y = pk2(a.z * scl, a.w * scl);
    u.z = pk2(b.x * scl, b.y * scl); u.w = pk2(b.z * scl, b.w * scl);
    *(uint4*)d = u;
}

// ---------------- QKV GEMM: m97-style staging + T2 swizzle -----------------
// z=0: Q (swapped, bias*QSCL, out (B,H,S,HD))
// z=1: K (swapped, out (B,H,S,HD))
// z=2: V (unswapped, out (B,H,HD,S))
// LDS dest linear (dma16 rule); global source chunk pre-swizzled with
// (row>>1)&3 so readback chunk = quad ^ ((lm>>1)&3) is 2-way conflict-free.
__global__ __launch_bounds__(256) void gemm_qkv_wa(
    const ushort* __restrict__ A,
    const ushort* __restrict__ W0, const ushort* __restrict__ W1,
    const ushort* __restrict__ W2,
    const float* __restrict__ B0, const float* __restrict__ B1,
    const float* __restrict__ B2,
    ushort* __restrict__ O0, ushort* __restrict__ O1, ushort* __restrict__ O2)
{
    __shared__ ushort As[128 * 32];
    __shared__ ushort Bs[128 * 32];
    __shared__ float bias_s[128];

    const int z = blockIdx.z;
    const ushort* W = (z == 0) ? W0 : (z == 1 ? W1 : W2);
    const float* bias = (z == 0) ? B0 : (z == 1 ? B1 : B2);
    ushort* out = (z == 0) ? O0 : (z == 1 ? O1 : O2);
    const bool isv = (z == 2);

    const int tid = threadIdx.x;
    const int bm = blockIdx.x * 128, bn = blockIdx.y * 128;
    const int wave = tid >> 6, lane = tid & 63, quad = lane >> 4, lm = lane & 15;
    const int r0 = tid >> 2, c0 = (tid & 3) * 8;
    // pre-swizzled global chunk: physical chunk (tid&3) holds logical
    // chunk (tid&3)^((r0>>1)&3).  (r0+64 has the same swizzle: 64 is even.)
    const int c0g = ((tid & 3) ^ ((tid >> 3) & 3)) * 8;
    // swizzled read chunk (row bases are multiples of 16 -> reduces to lm)
    const int csw8 = (quad ^ ((lm >> 1) & 3)) * 8;

    if (tid < 128) {
        float bb = bias[bn + tid];
        if (z == 0) bb *= QSCL;
        bias_s[tid] = bb;
    }

    const floatx4 zz = {0.f, 0.f, 0.f, 0.f};
    floatx4 acc[16];
#pragma unroll
    for (int i = 0; i < 16; ++i) acc[i] = zz;

    // running pointers: strength-reduced dma16 addressing (+32/step)
    const ushort* a0 = A + (size_t)(bm + r0) * DD + c0g;
    const ushort* a1 = A + (size_t)(bm + 64 + r0) * DD + c0g;
    const ushort* w0 = W + (size_t)(bn + r0) * DD + c0g;
    const ushort* w1 = W + (size_t)(bn + 64 + r0) * DD + c0g;
    ushort* const lA0 = &As[r0 * 32 + c0];
    ushort* const lA1 = &As[(64 + r0) * 32 + c0];
    ushort* const lB0 = &Bs[r0 * 32 + c0];
    ushort* const lB1 = &Bs[(64 + r0) * 32 + c0];

    for (int k0 = 0; k0 < DD; k0 += 32) {
        __syncthreads();
        dma16(lA0, a0); dma16(lA1, a1);
        dma16(lB0, w0); dma16(lB1, w1);
        a0 += 32; a1 += 32; w0 += 32; w1 += 32;
        __syncthreads();

        if (isv) {
            const short8 bf0 = *(const short8*)&Bs[(wave * 32 + lm) * 32 + csw8];
            const short8 bf1 = *(const short8*)&Bs[(wave * 32 + 16 + lm) * 32 + csw8];
#pragma unroll
            for (int i = 0; i < 8; ++i) {
                const short8 af = *(const short8*)&As[(i * 16 + lm) * 32 + csw8];
                acc[i * 2 + 0] = __builtin_amdgcn_mfma_f32_16x16x32_bf16(
                    af, bf0, acc[i * 2 + 0], 0, 0, 0);
                acc[i * 2 + 1] = __builtin_amdgcn_mfma_f32_16x16x32_bf16(
                    af, bf1, acc[i * 2 + 1], 0, 0, 0);
            }
        } else {
            const short8 af0 = *(const short8*)&As[(wave * 32 + lm) * 32 + csw8];
            const short8 af1 = *(const short8*)&As[(wave * 32 + 16 + lm) * 32 + csw8];
#pragma unroll
            for (int j = 0; j < 8; ++j) {
                const short8 bf = *(const short8*)&Bs[(j * 16 + lm) * 32 + csw8];
                acc[j] = __builtin_amdgcn_mfma_f32_16x16x32_bf16(
                    bf, af0, acc[j], 0, 0, 0);
                acc[8 + j] = __builtin_amdgcn_mfma_f32_16x16x32_bf16(
                    bf, af1, acc[8 + j], 0, 0, 0);
            }
        }
    }

    if (isv) {
        // V: n-row per lane, 4 consecutive s per reg; 32B contiguous/instr.
        const int b = bm >> 11, sbase = bm & 2047;
#pragma unroll
        for (int j = 0; j < 2; ++j) {
            const int n = bn + wave * 32 + j * 16 + lm;
            const float bb = bias_s[n - bn];
            ushort* orow = out + ((size_t)(b * DD + n)) * SS;
#pragma unroll
            for (int i = 0; i < 8; ++i) {
                const floatx4 a = acc[i * 2 + j];
                ushort4 v;
                v.x = f2bf(a[0] + bb); v.y = f2bf(a[1] + bb);
                v.z = f2bf(a[2] + bb); v.w = f2bf(a[3] + bb);
                *(ushort4*)(orow + sbase + i * 16 + quad * 4) = v;
            }
        }
    } else {
        // Q/K: m-row per lane, 4 consecutive hd per reg; 32B contiguous/instr.
#pragma unroll
        for (int i = 0; i < 2; ++i) {
            const int m = bm + wave * 32 + i * 16 + lm;
            const int b = m >> 11, s = m & 2047;
#pragma unroll
            for (int j = 0; j < 8; ++j) {
                const int nl = j * 16 + quad * 4;
                const int n = bn + nl;
                const int h = n >> 6, hd = n & 63;
                const floatx4 a = acc[i * 8 + j];
                ushort4 v;
                v.x = f2bf(a[0] + bias_s[nl + 0]);
                v.y = f2bf(a[1] + bias_s[nl + 1]);
                v.z = f2bf(a[2] + bias_s[nl + 2]);
                v.w = f2bf(a[3] + bias_s[nl + 3]);
                *(ushort4*)(out + (((size_t)(b * HH + h) * SS) + s) * HDD + hd) = v;
            }
        }
    }
}

// ---------------- proj GEMM: 128x128, reg-staged (R13) + T2 swizzle --------
// swapped MFMA: regs = 4 consecutive n; quads give full 64B-line stores.
// Vector LDS stores -> swizzle the LDS write chunk directly.
__global__ __launch_bounds__(256, 2) void gemm_proj_rs(
    const ushort* __restrict__ A, const ushort* __restrict__ W,
    const float* __restrict__ bias, float* __restrict__ out)
{
    __shared__ ushort As[128 * 32];
    __shared__ ushort Bs[128 * 32];
    __shared__ float bias_s[128];

    const int tid = threadIdx.x;
    const int bm = blockIdx.x * 128, bn = blockIdx.y * 128;
    const int wave = tid >> 6, lane = tid & 63, quad = lane >> 4, lm = lane & 15;
    const int wm = wave >> 1, wn = wave & 1;
    const int r0 = tid >> 2, c0 = (tid & 3) * 8;
    const int c0s = ((tid & 3) ^ ((tid >> 3) & 3)) * 8;   // swizzled LDS chunk
    const int csw8 = (quad ^ ((lm >> 1) & 3)) * 8;        // swizzled read chunk

    if (tid < 128) bias_s[tid] = bias[bn + tid];

    const floatx4 zz = {0.f, 0.f, 0.f, 0.f};
    floatx4 acc[4][4];
#pragma unroll
    for (int i = 0; i < 4; ++i)
#pragma unroll
        for (int j = 0; j < 4; ++j) acc[i][j] = zz;

    const ushort* ap = A + (size_t)(bm + r0) * DD + c0;
    const ushort* wpp = W + (size_t)(bn + r0) * DD + c0;

    uint4 ar0, ar1, wr0, wr1;
#define LOADT(K0)                                                \
    do {                                                         \
        ar0 = *(const uint4*)(ap + (K0));                        \
        ar1 = *(const uint4*)(ap + (size_t)64 * DD + (K0));      \
        wr0 = *(const uint4*)(wpp + (K0));                       \
        wr1 = *(const uint4*)(wpp + (size_t)64 * DD + (K0));     \
    } while (0)
#define STORET()                                                 \
    do {                                                         \
        *(uint4*)&As[r0 * 32 + c0s] = ar0;                       \
        *(uint4*)&As[(64 + r0) * 32 + c0s] = ar1;                \
        *(uint4*)&Bs[r0 * 32 + c0s] = wr0;                       \
        *(uint4*)&Bs[(64 + r0) * 32 + c0s] = wr1;                \
    } while (0)

    LOADT(0);
    STORET();
    __syncthreads();

    for (int k0 = 0; k0 < DD; k0 += 32) {
        const bool have_nxt = (k0 + 32) < DD;
        if (have_nxt) LOADT(k0 + 32);  // prefetch: latency hides under MFMA

        short8 af[4], bf[4];
#pragma unroll
        for (int i = 0; i < 4; ++i)
            af[i] = *(const short8*)&As[(wm * 64 + i * 16 + lm) * 32 + csw8];
#pragma unroll
        for (int j = 0; j < 4; ++j)
            bf[j] = *(const short8*)&Bs[(wn * 64 + j * 16 + lm) * 32 + csw8];
#pragma unroll
        for (int i = 0; i < 4; ++i)
#pragma unroll
            for (int j = 0; j < 4; ++j)
                acc[i][j] = __builtin_amdgcn_mfma_f32_16x16x32_bf16(
                    bf[j], af[i], acc[i][j], 0, 0, 0);

        if (have_nxt) {
            __syncthreads();
            STORET();
            __syncthreads();
        }
    }
#undef LOADT
#undef STORET

#pragma unroll
    for (int i = 0; i < 4; ++i) {
#pragma unroll
        for (int j = 0; j < 4; ++j) {
            const int nl = wn * 64 + j * 16 + quad * 4;
            const int n = bn + nl;
            const int m = bm + wm * 64 + i * 16 + lm;
            float4 v;
            v.x = acc[i][j][0] + bias_s[nl + 0];
            v.y = acc[i][j][1] + bias_s[nl + 1];
            v.z = acc[i][j][2] + bias_s[nl + 2];
            v.w = acc[i][j][3] + bias_s[nl + 3];
            *(float4*)(out + (size_t)m * DD + n) = v;
        }
    }
}

// ---------------- Attention: swapped MFMA, split-K x2 (R10) ----------------
// Q,K: (B*H,S,HD) bf16 (Q pre-scaled by QSCL -> logits are log2-domain).
// Vt: (B*H,HD,S) bf16.
// Opart: 2 x (B,S,D) bf16 unnormalized. lbuf: 2 x (B*H*S) f32.
__global__ __launch_bounds__(256) void attn_mfma(
    const ushort* __restrict__ Q, const ushort* __restrict__ K,
    const ushort* __restrict__ Vt, const int* __restrict__ am,
    ushort* __restrict__ Opart, float* __restrict__ lbuf)
{
    __shared__ ushort Ks[64 * 72];
    __shared__ ushort Vts[64 * 72];
    __shared__ ushort Ps[4][32 * 72];
    __shared__ int amk_s[64];

    const int tid = threadIdx.x;
    const int wq = tid >> 6, lane = tid & 63, quad = lane >> 4, lm = lane & 15;
    const int bh = blockIdx.y, b = bh >> 4, h = bh & 15;
    // Balance: same-CU blocks are {same x, both b, both splits}. qt = b?x:15-x
    // pairs workloads (x+1)+(16-x)=17 tiles/split on every CU.
    const int qt = b ? (int)blockIdx.x : (int)(gridDim.x - 1 - blockIdx.x);
    const int split = blockIdx.z;
    const size_t base = (size_t)bh * SS * HDD;
    const size_t tbase = (size_t)bh * HDD * SS;
    const int* amrow = am + b * SS;
    const int q0 = qt * 128 + wq * 32;

    short8 qf[2][2];
#pragma unroll
    for (int sub = 0; sub < 2; ++sub) {
        const ushort* qp = Q + base + (size_t)(q0 + sub * 16 + lm) * HDD + quad * 8;
        qf[sub][0] = *(const short8*)qp;
        qf[sub][1] = *(const short8*)(qp + 32);
    }
    int amq[2];
#pragma unroll
    for (int sub = 0; sub < 2; ++sub) amq[sub] = amrow[q0 + sub * 16 + lm];
    const bool allq = __all(amq[0] != 0 && amq[1] != 0);

    const floatx4 zz = {0.f, 0.f, 0.f, 0.f};
    floatx4 o_acc[2][4];
#pragma unroll
    for (int sub = 0; sub < 2; ++sub)
#pragma unroll
        for (int n2 = 0; n2 < 4; ++n2) o_acc[sub][n2] = zz;
    float l_lane[2] = {0.f, 0.f};

    const int sr = tid >> 2, sc = (tid & 3) * 16;
    const int ktmax = 2 * qt + 1;

    // ---- prologue: stage first tile ----
    uint4 kra, krb, vra, vrb;
    int amr = 1;
    {
        const ushort* kp = K + base + (size_t)(split * 64 + sr) * HDD + sc;
        kra = ((const uint4*)kp)[0]; krb = ((const uint4*)kp)[1];
        const ushort* vp = Vt + tbase + (size_t)sr * SS + split * 64 + sc;
        vra = ((const uint4*)vp)[0]; vrb = ((const uint4*)vp)[1];
        if (tid < 64) amr = amrow[split * 64 + tid];
    }
    *(uint4*)&Ks[sr * 72 + sc] = kra;
    *(uint4*)&Ks[sr * 72 + sc + 8] = krb;
    *(uint4*)&Vts[sr * 72 + sc] = vra;
    *(uint4*)&Vts[sr * 72 + sc + 8] = vrb;
    if (tid < 64) amk_s[tid] = amr;
    __syncthreads();

    for (int kt = split; kt <= ktmax; kt += 2) {
        const int nxt = kt + 2;
        const bool have_nxt = nxt <= ktmax;
        // T14: issue next tile's global loads now; LDS writes after barrier.
        if (have_nxt) {
            const ushort* kp = K + base + (size_t)(nxt * 64 + sr) * HDD + sc;
            kra = ((const uint4*)kp)[0]; krb = ((const uint4*)kp)[1];
            const ushort* vp = Vt + tbase + (size_t)sr * SS + nxt * 64 + sc;
            vra = ((const uint4*)vp)[0]; vrb = ((const uint4*)vp)[1];
            if (tid < 64) amr = amrow[nxt * 64 + tid];
        }

        // ---- S^T = K Q^T (swapped): regs = 4 consecutive t ----
        const bool allk = (__ballot(amk_s[lane] != 0) == ~0ull);
        const bool fast = allk & allq & ((kt * 64 + 63) <= q0);
        if (fast) {
#pragma unroll
            for (int nt = 0; nt < 4; ++nt) {
                const short8 kf0 = *(const short8*)&Ks[(nt * 16 + lm) * 72 + quad * 8];
                const short8 kf1 = *(const short8*)&Ks[(nt * 16 + lm) * 72 + 32 + quad * 8];
#pragma unroll
                for (int sub = 0; sub < 2; ++sub) {
                    floatx4 s = zz;
                    s = __builtin_amdgcn_mfma_f32_16x16x32_bf16(kf0, qf[sub][0], s, 0, 0, 0);
                    s = __builtin_amdgcn_mfma_f32_16x16x32_bf16(kf1, qf[sub][1], s, 0, 0, 0);
                    const float e0 = exp2f(fminf(s[0], 40.f));
                    const float e1 = exp2f(fminf(s[1], 40.f));
                    const float e2 = exp2f(fminf(s[2], 40.f));
                    const float e3 = exp2f(fminf(s[3], 40.f));
                    l_lane[sub] += (e0 + e1) + (e2 + e3);
                    uint2 pv;
                    pv.x = cvtpk(e0, e1); pv.y = cvtpk(e2, e3);
                    *(uint2*)&Ps[wq][(sub * 16 + lm) * 72 + nt * 16 + quad * 4] = pv;
                }
            }
        } else {
#pragma unroll
            for (int nt = 0; nt < 4; ++nt) {
                const short8 kf0 = *(const short8*)&Ks[(nt * 16 + lm) * 72 + quad * 8];
                const short8 kf1 = *(const short8*)&Ks[(nt * 16 + lm) * 72 + 32 + quad * 8];
                const int4 amk4 = *(const int4*)&amk_s[nt * 16 + quad * 4];
#pragma unroll
                for (int sub = 0; sub < 2; ++sub) {
                    floatx4 s = zz;
                    s = __builtin_amdgcn_mfma_f32_16x16x32_bf16(kf0, qf[sub][0], s, 0, 0, 0);
                    s = __builtin_amdgcn_mfma_f32_16x16x32_bf16(kf1, qf[sub][1], s, 0, 0, 0);
                    const int qg = q0 + sub * 16 + lm;
                    const int t0 = kt * 64 + nt * 16 + quad * 4;
                    const bool mq = amq[sub] != 0;
                    const bool ok0 = amk4.x && mq && (t0 + 0 <= qg);
                    const bool ok1 = amk4.y && mq && (t0 + 1 <= qg);
                    const bool ok2 = amk4.z && mq && (t0 + 2 <= qg);
                    const bool ok3 = amk4.w && mq && (t0 + 3 <= qg);
                    const float e0 = exp2f(fminf(ok0 ? s[0] : NEG_BIG, 40.f));
                    const float e1 = exp2f(fminf(ok1 ? s[1] : NEG_BIG, 40.f));
                    const float e2 = exp2f(fminf(ok2 ? s[2] : NEG_BIG, 40.f));
                    const float e3 = exp2f(fminf(ok3 ? s[3] : NEG_BIG, 40.f));
                    l_lane[sub] += (e0 + e1) + (e2 + e3);
                    uint2 pv;
                    pv.x = cvtpk(e0, e1); pv.y = cvtpk(e2, e3);
                    *(uint2*)&Ps[wq][(sub * 16 + lm) * 72 + nt * 16 + quad * 4] = pv;
                }
            }
        }

        // ---- O^T += V^T P^T (swapped): regs = 4 consecutive hd ----
        short8 af[2][2];
#pragma unroll
        for (int sub = 0; sub < 2; ++sub) {
            af[sub][0] = *(const short8*)&Ps[wq][(sub * 16 + lm) * 72 + quad * 8];
            af[sub][1] = *(const short8*)&Ps[wq][(sub * 16 + lm) * 72 + 32 + quad * 8];
        }
#pragma unroll
        for (int n2 = 0; n2 < 4; ++n2) {
            const short8 vf0 = *(const short8*)&Vts[(n2 * 16 + lm) * 72 + quad * 8];
            const short8 vf1 = *(const short8*)&Vts[(n2 * 16 + lm) * 72 + 32 + quad * 8];
#pragma unroll
            for (int sub = 0; sub < 2; ++sub) {
                o_acc[sub][n2] = __builtin_amdgcn_mfma_f32_16x16x32_bf16(
                    vf0, af[sub][0], o_acc[sub][n2], 0, 0, 0);
                o_acc[sub][n2] = __builtin_amdgcn_mfma_f32_16x16x32_bf16(
                    vf1, af[sub][1], o_acc[sub][n2], 0, 0, 0);
            }
        }

        if (have_nxt) {
            __syncthreads();  // all waves done reading Ks/Vts/amk_s
            *(uint4*)&Ks[sr * 72 + sc] = kra;
            *(uint4*)&Ks[sr * 72 + sc + 8] = krb;
            *(uint4*)&Vts[sr * 72 + sc] = vra;
            *(uint4*)&Vts[sr * 72 + sc + 8] = vrb;
            if (tid < 64) amk_s[tid] = amr;
            __syncthreads();  // next tile ready
        }
    }

    // ---- l: sum across quads (lane's l covers its t-subset; q = lm) ----
#pragma unroll
    for (int sub = 0; sub < 2; ++sub) {
        float l = l_lane[sub];
        l += __shfl_xor(l, 16);
        l += __shfl_xor(l, 32);
        if (quad == 0)
            lbuf[(size_t)split * (BB * HH * SS) + (size_t)bh * SS + q0 + sub * 16 + lm] = l;
        // ---- epilogue: unnormalized O, packed 4 consecutive hd ----
        const int srow = q0 + sub * 16 + lm;
#pragma unroll
        for (int n2 = 0; n2 < 4; ++n2) {
            uint2 v;
            v.x = cvtpk(o_acc[sub][n2][0], o_acc[sub][n2][1]);
            v.y = cvtpk(o_acc[sub][n2][2], o_acc[sub][n2][3]);
            *(uint2*)(Opart + (size_t)split * (BB * SS * DD)
                        + ((size_t)(b * SS + srow)) * DD + h * HDD + n2 * 16 + quad * 4) = v;
        }
    }
}

// ---------------- combine: A = (O0 + O1) / (l0 + l1), bf16 ----------------
__global__ __launch_bounds__(256) void combine(
    const ushort* __restrict__ Opart, const float* __restrict__ lbuf,
    ushort* __restrict__ Aout)
{
    const size_t e = ((size_t)blockIdx.x * 256 + threadIdx.x) * 8;
    const int m = (int)(e >> 10);
    const int col = (int)(e & 1023);
    const int b = m >> 11, s = m & 2047, h = col >> 6;
    const float l = lbuf[(b * HH + h) * SS + s]
                  + lbuf[BB * HH * SS + (b * HH + h) * SS + s];
    const float inv = l > 0.f ? 1.f / l : 0.f;
    const uint4 u0 = *(const uint4*)(Opart + e);
    const uint4 u1 = *(const uint4*)(Opart + (size_t)BB * SS * DD + e);
    float f0[8], f1[8];
    unpack8(u0, f0);
    unpack8(u1, f1);
    uint4 o;
    o.x = pk2((f0[0] + f1[0]) * inv, (f0[1] + f1[1]) * inv);
    o.y = pk2((f0[2] + f1[2]) * inv, (f0[3] + f1[3]) * inv);
    o.z = pk2((f0[4] + f1[4]) * inv, (f0[5] + f1[5]) * inv);
    o.w = pk2((f0[6] + f1[6]) * inv, (f0[7] + f1[7]) * inv);
    *(uint4*)(Aout + e) = o;
}

extern "C" void kernel_launch(void* const* d_in, const int* in_sizes, int n_in,
                              void* d_out, int out_size, void* d_ws, size_t ws_size,
                              hipStream_t stream) {
    const float* x  = (const float*)d_in[0];
    const int*   am = (const int*)d_in[1];
    const float* Wq = (const float*)d_in[2];
    const float* bq = (const float*)d_in[3];
    const float* Wk = (const float*)d_in[4];
    const float* bk = (const float*)d_in[5];
    const float* Wv = (const float*)d_in[6];
    const float* bv = (const float*)d_in[7];
    const float* Wp = (const float*)d_in[8];
    const float* bp = (const float*)d_in[9];
    float* out = (float*)d_out;

    const size_t elems = (size_t)BB * HH * SS * HDD;  // 4M
    ushort* q_ws = (ushort*)d_ws;                 // Q; later combined A
    ushort* k_ws = q_ws + elems;
    ushort* v_ws = k_ws + elems;                  // V^T (B,H,HD,S)
    float*  lbuf = (float*)(v_ws + elems);        // 2 x 256 KB in a_ws slot
    ushort* wpb  = (ushort*)(lbuf + 2 * BB * HH * SS);  // bf16 Wp (2 MB)

    // d_out scratch: bf16 x (4M) + Wq/Wk/Wv (1M each); later attn partials
    ushort* xb  = (ushort*)d_out;
    ushort* wqb = xb + 4194304;
    ushort* wkb = wqb + 1048576;
    ushort* wvb = wkb + 1048576;

    cvt_all<<<4096, 256, 0, stream>>>(x, Wq, Wk, Wv, Wp, xb, wpb);

    gemm_qkv_wa<<<dim3(32, 8, 3), 256, 0, stream>>>(
        xb, wqb, wkb, wvb, bq, bk, bv, q_ws, k_ws, v_ws);

    attn_mfma<<<dim3(SS / 128, BB * HH, 2), 256, 0, stream>>>(
        q_ws, k_ws, v_ws, am, (ushort*)d_out, lbuf);

    combine<<<2048, 256, 0, stream>>>((const ushort*)d_out, lbuf, q_ws);

    gemm_proj_rs<<<dim3(32, 8), 256, 0, stream>>>(q_ws, wpb, bp, out);
}

// Round 12
// 215.985 us; speedup vs baseline: 1.5518x; 1.0097x over previous
//
#include <hip/hip_runtime.h>

// MHA forward: B=2, S=2048, D=1024, H=16, HD=64. Inputs f32, mask int32,
// OUTPUT f32. Intermediates bf16.
//
// Round 20: fix attn RESIDENCY imbalance (the 17.7% occupancy).
//   Old: same-CU blocks had work {x+1,x+1,16-x,16-x} -- CU-total balanced
//   but short blocks exit early -> CU runs mostly half-empty (x=0: 2 blocks
//   for 15/16 of the time). New: q-granularity 64 rows; each block runs TWO
//   q-tiles sequentially (qtA=pslot, qtB=31-pslot) -> 33 kt-tiles per
//   split-pair for EVERY block. Uniform duration -> 4 blocks/CU resident
//   end-to-end. Same math: 4 waves x 16 rows/phase (sub-loop removed),
//   Ps halves -> LDS 27.3KB. Grid unchanged (16,32,2).
//  - GEMMs / cvt / combine: R19 (swizzled, 218.1us baseline).

#define BB 2
#define SS 2048
#define DD 1024
#define HH 16
#define HDD 64
#define NEG_BIG (-1.0e30f)
#define QSCL 0.18033688011112042f  // 0.125 * log2(e)

typedef __attribute__((ext_vector_type(8))) short short8;
typedef __attribute__((ext_vector_type(4))) float floatx4;
typedef unsigned int u32;
#define AS_GLOBAL __attribute__((address_space(1)))
#define AS_LDS    __attribute__((address_space(3)))

__device__ __forceinline__ ushort f2bf(float f) {  // RNE
    unsigned u = __float_as_uint(f);
    u += 0x7fffu + ((u >> 16) & 1u);
    return (ushort)(u >> 16);
}
__device__ __forceinline__ unsigned pk2(float a, float b) {
    return ((unsigned)f2bf(b) << 16) | (unsigned)f2bf(a);
}
__device__ __forceinline__ unsigned cvtpk(float a, float b) {  // lo=a, hi=b, RNE
    unsigned r;
    asm("v_cvt_pk_bf16_f32 %0, %1, %2" : "=v"(r) : "v"(a), "v"(b));
    return r;
}
__device__ __forceinline__ void unpack8(const uint4 u, float* d) {
    d[0] = __uint_as_float(u.x << 16);
    d[1] = __uint_as_float(u.x & 0xffff0000u);
    d[2] = __uint_as_float(u.y << 16);
    d[3] = __uint_as_float(u.y & 0xffff0000u);
    d[4] = __uint_as_float(u.z << 16);
    d[5] = __uint_as_float(u.z & 0xffff0000u);
    d[6] = __uint_as_float(u.w << 16);
    d[7] = __uint_as_float(u.w & 0xffff0000u);
}
__device__ __forceinline__ void dma16(void* lds, const void* g) {
    __builtin_amdgcn_global_load_lds((const AS_GLOBAL u32*)g, (AS_LDS u32*)lds,
                                     16, 0, 0);
}

// ---------------- f32 -> bf16 conversion (x, Wq, Wk, Wv, Wp) ----------------
// Wq is pre-scaled by QSCL (attention scale + log2e folded into Q).
__global__ __launch_bounds__(256) void cvt_all(
    const float* __restrict__ x, const float* __restrict__ wq,
    const float* __restrict__ wk, const float* __restrict__ wv,
    const float* __restrict__ wp,
    ushort* __restrict__ dst, ushort* __restrict__ wp_dst)
{
    const size_t flat = ((size_t)blockIdx.x * 256 + threadIdx.x) * 8;
    const float* s;
    ushort* d = dst + flat;
    size_t off;
    float scl = 1.0f;
    if (flat < (size_t)4194304)      { s = x;  off = flat; }
    else if (flat < (size_t)5242880) { s = wq; off = flat - 4194304; scl = QSCL; }
    else if (flat < (size_t)6291456) { s = wk; off = flat - 5242880; }
    else if (flat < (size_t)7340032) { s = wv; off = flat - 6291456; }
    else { s = wp; off = flat - 7340032; d = wp_dst + off; }
    const float4 a = ((const float4*)(s + off))[0];
    const float4 b = ((const float4*)(s + off))[1];
    uint4 u;
    u.x = pk2(a.x * scl, a.y * scl); u.y = pk2(a.z * scl, a.w * scl);
    u.z = pk2(b.x * scl, b.y * scl); u.w = pk2(b.z * scl, b.w * scl);
    *(uint4*)d = u;
}

// ---------------- QKV GEMM: m97-style staging + T2 swizzle (R19) -----------
__global__ __launch_bounds__(256) void gemm_qkv_wa(
    const ushort* __restrict__ A,
    const ushort* __restrict__ W0, const ushort* __restrict__ W1,
    const ushort* __restrict__ W2,
    const float* __restrict__ B0, const float* __restrict__ B1,
    const float* __restrict__ B2,
    ushort* __restrict__ O0, ushort* __restrict__ O1, ushort* __restrict__ O2)
{
    __shared__ ushort As[128 * 32];
    __shared__ ushort Bs[128 * 32];
    __shared__ float bias_s[128];

    const int z = blockIdx.z;
    const ushort* W = (z == 0) ? W0 : (z == 1 ? W1 : W2);
    const float* bias = (z == 0) ? B0 : (z == 1 ? B1 : B2);
    ushort* out = (z == 0) ? O0 : (z == 1 ? O1 : O2);
    const bool isv = (z == 2);

    const int tid = threadIdx.x;
    const int bm = blockIdx.x * 128, bn = blockIdx.y * 128;
    const int wave = tid >> 6, lane = tid & 63, quad = lane >> 4, lm = lane & 15;
    const int r0 = tid >> 2, c0 = (tid & 3) * 8;
    const int c0g = ((tid & 3) ^ ((tid >> 3) & 3)) * 8;
    const int csw8 = (quad ^ ((lm >> 1) & 3)) * 8;

    if (tid < 128) {
        float bb = bias[bn + tid];
        if (z == 0) bb *= QSCL;
        bias_s[tid] = bb;
    }

    const floatx4 zz = {0.f, 0.f, 0.f, 0.f};
    floatx4 acc[16];
#pragma unroll
    for (int i = 0; i < 16; ++i) acc[i] = zz;

    const ushort* a0 = A + (size_t)(bm + r0) * DD + c0g;
    const ushort* a1 = A + (size_t)(bm + 64 + r0) * DD + c0g;
    const ushort* w0 = W + (size_t)(bn + r0) * DD + c0g;
    const ushort* w1 = W + (size_t)(bn + 64 + r0) * DD + c0g;
    ushort* const lA0 = &As[r0 * 32 + c0];
    ushort* const lA1 = &As[(64 + r0) * 32 + c0];
    ushort* const lB0 = &Bs[r0 * 32 + c0];
    ushort* const lB1 = &Bs[(64 + r0) * 32 + c0];

    for (int k0 = 0; k0 < DD; k0 += 32) {
        __syncthreads();
        dma16(lA0, a0); dma16(lA1, a1);
        dma16(lB0, w0); dma16(lB1, w1);
        a0 += 32; a1 += 32; w0 += 32; w1 += 32;
        __syncthreads();

        if (isv) {
            const short8 bf0 = *(const short8*)&Bs[(wave * 32 + lm) * 32 + csw8];
            const short8 bf1 = *(const short8*)&Bs[(wave * 32 + 16 + lm) * 32 + csw8];
#pragma unroll
            for (int i = 0; i < 8; ++i) {
                const short8 af = *(const short8*)&As[(i * 16 + lm) * 32 + csw8];
                acc[i * 2 + 0] = __builtin_amdgcn_mfma_f32_16x16x32_bf16(
                    af, bf0, acc[i * 2 + 0], 0, 0, 0);
                acc[i * 2 + 1] = __builtin_amdgcn_mfma_f32_16x16x32_bf16(
                    af, bf1, acc[i * 2 + 1], 0, 0, 0);
            }
        } else {
            const short8 af0 = *(const short8*)&As[(wave * 32 + lm) * 32 + csw8];
            const short8 af1 = *(const short8*)&As[(wave * 32 + 16 + lm) * 32 + csw8];
#pragma unroll
            for (int j = 0; j < 8; ++j) {
                const short8 bf = *(const short8*)&Bs[(j * 16 + lm) * 32 + csw8];
                acc[j] = __builtin_amdgcn_mfma_f32_16x16x32_bf16(
                    bf, af0, acc[j], 0, 0, 0);
                acc[8 + j] = __builtin_amdgcn_mfma_f32_16x16x32_bf16(
                    bf, af1, acc[8 + j], 0, 0, 0);
            }
        }
    }

    if (isv) {
        const int b = bm >> 11, sbase = bm & 2047;
#pragma unroll
        for (int j = 0; j < 2; ++j) {
            const int n = bn + wave * 32 + j * 16 + lm;
            const float bb = bias_s[n - bn];
            ushort* orow = out + ((size_t)(b * DD + n)) * SS;
#pragma unroll
            for (int i = 0; i < 8; ++i) {
                const floatx4 a = acc[i * 2 + j];
                ushort4 v;
                v.x = f2bf(a[0] + bb); v.y = f2bf(a[1] + bb);
                v.z = f2bf(a[2] + bb); v.w = f2bf(a[3] + bb);
                *(ushort4*)(orow + sbase + i * 16 + quad * 4) = v;
            }
        }
    } else {
#pragma unroll
        for (int i = 0; i < 2; ++i) {
            const int m = bm + wave * 32 + i * 16 + lm;
            const int b = m >> 11, s = m & 2047;
#pragma unroll
            for (int j = 0; j < 8; ++j) {
                const int nl = j * 16 + quad * 4;
                const int n = bn + nl;
                const int h = n >> 6, hd = n & 63;
                const floatx4 a = acc[i * 8 + j];
                ushort4 v;
                v.x = f2bf(a[0] + bias_s[nl + 0]);
                v.y = f2bf(a[1] + bias_s[nl + 1]);
                v.z = f2bf(a[2] + bias_s[nl + 2]);
                v.w = f2bf(a[3] + bias_s[nl + 3]);
                *(ushort4*)(out + (((size_t)(b * HH + h) * SS) + s) * HDD + hd) = v;
            }
        }
    }
}

// ---------------- proj GEMM: 128x128, reg-staged + T2 swizzle (R19) --------
__global__ __launch_bounds__(256, 2) void gemm_proj_rs(
    const ushort* __restrict__ A, const ushort* __restrict__ W,
    const float* __restrict__ bias, float* __restrict__ out)
{
    __shared__ ushort As[128 * 32];
    __shared__ ushort Bs[128 * 32];
    __shared__ float bias_s[128];

    const int tid = threadIdx.x;
    const int bm = blockIdx.x * 128, bn = blockIdx.y * 128;
    const int wave = tid >> 6, lane = tid & 63, quad = lane >> 4, lm = lane & 15;
    const int wm = wave >> 1, wn = wave & 1;
    const int r0 = tid >> 2, c0 = (tid & 3) * 8;
    const int c0s = ((tid & 3) ^ ((tid >> 3) & 3)) * 8;
    const int csw8 = (quad ^ ((lm >> 1) & 3)) * 8;

    if (tid < 128) bias_s[tid] = bias[bn + tid];

    const floatx4 zz = {0.f, 0.f, 0.f, 0.f};
    floatx4 acc[4][4];
#pragma unroll
    for (int i = 0; i < 4; ++i)
#pragma unroll
        for (int j = 0; j < 4; ++j) acc[i][j] = zz;

    const ushort* ap = A + (size_t)(bm + r0) * DD + c0;
    const ushort* wpp = W + (size_t)(bn + r0) * DD + c0;

    uint4 ar0, ar1, wr0, wr1;
#define LOADT(K0)                                                \
    do {                                                         \
        ar0 = *(const uint4*)(ap + (K0));                        \
        ar1 = *(const uint4*)(ap + (size_t)64 * DD + (K0));      \
        wr0 = *(const uint4*)(wpp + (K0));                       \
        wr1 = *(const uint4*)(wpp + (size_t)64 * DD + (K0));     \
    } while (0)
#define STORET()                                                 \
    do {                                                         \
        *(uint4*)&As[r0 * 32 + c0s] = ar0;                       \
        *(uint4*)&As[(64 + r0) * 32 + c0s] = ar1;                \
        *(uint4*)&Bs[r0 * 32 + c0s] = wr0;                       \
        *(uint4*)&Bs[(64 + r0) * 32 + c0s] = wr1;                \
    } while (0)

    LOADT(0);
    STORET();
    __syncthreads();

    for (int k0 = 0; k0 < DD; k0 += 32) {
        const bool have_nxt = (k0 + 32) < DD;
        if (have_nxt) LOADT(k0 + 32);

        short8 af[4], bf[4];
#pragma unroll
        for (int i = 0; i < 4; ++i)
            af[i] = *(const short8*)&As[(wm * 64 + i * 16 + lm) * 32 + csw8];
#pragma unroll
        for (int j = 0; j < 4; ++j)
            bf[j] = *(const short8*)&Bs[(wn * 64 + j * 16 + lm) * 32 + csw8];
#pragma unroll
        for (int i = 0; i < 4; ++i)
#pragma unroll
            for (int j = 0; j < 4; ++j)
                acc[i][j] = __builtin_amdgcn_mfma_f32_16x16x32_bf16(
                    bf[j], af[i], acc[i][j], 0, 0, 0);

        if (have_nxt) {
            __syncthreads();
            STORET();
            __syncthreads();
        }
    }
#undef LOADT
#undef STORET

#pragma unroll
    for (int i = 0; i < 4; ++i) {
#pragma unroll
        for (int j = 0; j < 4; ++j) {
            const int nl = wn * 64 + j * 16 + quad * 4;
            const int n = bn + nl;
            const int m = bm + wm * 64 + i * 16 + lm;
            float4 v;
            v.x = acc[i][j][0] + bias_s[nl + 0];
            v.y = acc[i][j][1] + bias_s[nl + 1];
            v.z = acc[i][j][2] + bias_s[nl + 2];
            v.w = acc[i][j][3] + bias_s[nl + 3];
            *(float4*)(out + (size_t)m * DD + n) = v;
        }
    }
}

// ---------------- Attention: uniform-work paired q-tiles, split-K x2 -------
// Each block: phase A = q-tile pslot (64 rows), phase B = q-tile 31-pslot.
// Tiles per split-pair = 33 for every block -> uniform duration, 4 blk/CU
// resident end-to-end. 4 waves x 16 rows per phase. Math identical to R10.
__global__ __launch_bounds__(256) void attn_mfma(
    const ushort* __restrict__ Q, const ushort* __restrict__ K,
    const ushort* __restrict__ Vt, const int* __restrict__ am,
    ushort* __restrict__ Opart, float* __restrict__ lbuf)
{
    __shared__ ushort Ks[64 * 72];
    __shared__ ushort Vts[64 * 72];
    __shared__ ushort Ps[4][16 * 72];
    __shared__ int amk_s[64];

    const int tid = threadIdx.x;
    const int wq = tid >> 6, lane = tid & 63, quad = lane >> 4, lm = lane & 15;
    const int bh = blockIdx.y, b = bh >> 4, h = bh & 15;
    const int pslot = (int)blockIdx.x;   // 0..15
    const int split = (int)blockIdx.z;   // 0,1
    const size_t base = (size_t)bh * SS * HDD;
    const size_t tbase = (size_t)bh * HDD * SS;
    const int* amrow = am + b * SS;
    const int sr = tid >> 2, sc = (tid & 3) * 16;
    const floatx4 zz = {0.f, 0.f, 0.f, 0.f};

#pragma unroll
    for (int ph = 0; ph < 2; ++ph) {
        const int qt64 = ph ? (31 - pslot) : pslot;
        const int q0 = qt64 * 64;
        const int ktend = qt64;          // causal: kt*64 <= q0+63
        const int qrow = q0 + wq * 16 + lm;

        if (ph) __syncthreads();  // phase A LDS reads done before B staging

        short8 qf0, qf1;
        {
            const ushort* qp = Q + base + (size_t)qrow * HDD + quad * 8;
            qf0 = *(const short8*)qp;
            qf1 = *(const short8*)(qp + 32);
        }
        const int amq = amrow[qrow];
        const bool allq = __all(amq != 0);

        floatx4 o_acc[4];
#pragma unroll
        for (int n2 = 0; n2 < 4; ++n2) o_acc[n2] = zz;
        float l_lane = 0.f;

        if (split <= ktend) {
            // ---- prologue: stage first tile ----
            uint4 kra, krb, vra, vrb;
            int amr = 1;
            {
                const ushort* kp = K + base + (size_t)(split * 64 + sr) * HDD + sc;
                kra = ((const uint4*)kp)[0]; krb = ((const uint4*)kp)[1];
                const ushort* vp = Vt + tbase + (size_t)sr * SS + split * 64 + sc;
                vra = ((const uint4*)vp)[0]; vrb = ((const uint4*)vp)[1];
                if (tid < 64) amr = amrow[split * 64 + tid];
            }
            *(uint4*)&Ks[sr * 72 + sc] = kra;
            *(uint4*)&Ks[sr * 72 + sc + 8] = krb;
            *(uint4*)&Vts[sr * 72 + sc] = vra;
            *(uint4*)&Vts[sr * 72 + sc + 8] = vrb;
            if (tid < 64) amk_s[tid] = amr;
            __syncthreads();

            for (int kt = split; kt <= ktend; kt += 2) {
                const int nxt = kt + 2;
                const bool have_nxt = nxt <= ktend;
                // T14: issue next tile's global loads; LDS writes after barrier.
                if (have_nxt) {
                    const ushort* kp = K + base + (size_t)(nxt * 64 + sr) * HDD + sc;
                    kra = ((const uint4*)kp)[0]; krb = ((const uint4*)kp)[1];
                    const ushort* vp = Vt + tbase + (size_t)sr * SS + nxt * 64 + sc;
                    vra = ((const uint4*)vp)[0]; vrb = ((const uint4*)vp)[1];
                    if (tid < 64) amr = amrow[nxt * 64 + tid];
                }

                // ---- S^T = K Q^T (swapped): regs = 4 consecutive t ----
                const bool allk = (__ballot(amk_s[lane] != 0) == ~0ull);
                const bool fast = allk & allq & ((kt * 64 + 63) <= (q0 + wq * 16));
                if (fast) {
#pragma unroll
                    for (int nt = 0; nt < 4; ++nt) {
                        const short8 kf0 = *(const short8*)&Ks[(nt * 16 + lm) * 72 + quad * 8];
                        const short8 kf1 = *(const short8*)&Ks[(nt * 16 + lm) * 72 + 32 + quad * 8];
                        floatx4 s = zz;
                        s = __builtin_amdgcn_mfma_f32_16x16x32_bf16(kf0, qf0, s, 0, 0, 0);
                        s = __builtin_amdgcn_mfma_f32_16x16x32_bf16(kf1, qf1, s, 0, 0, 0);
                        const float e0 = exp2f(fminf(s[0], 40.f));
                        const float e1 = exp2f(fminf(s[1], 40.f));
                        const float e2 = exp2f(fminf(s[2], 40.f));
                        const float e3 = exp2f(fminf(s[3], 40.f));
                        l_lane += (e0 + e1) + (e2 + e3);
                        uint2 pv;
                        pv.x = cvtpk(e0, e1); pv.y = cvtpk(e2, e3);
                        *(uint2*)&Ps[wq][lm * 72 + nt * 16 + quad * 4] = pv;
                    }
                } else {
#pragma unroll
                    for (int nt = 0; nt < 4; ++nt) {
                        const short8 kf0 = *(const short8*)&Ks[(nt * 16 + lm) * 72 + quad * 8];
                        const short8 kf1 = *(const short8*)&Ks[(nt * 16 + lm) * 72 + 32 + quad * 8];
                        const int4 amk4 = *(const int4*)&amk_s[nt * 16 + quad * 4];
                        floatx4 s = zz;
                        s = __builtin_amdgcn_mfma_f32_16x16x32_bf16(kf0, qf0, s, 0, 0, 0);
                        s = __builtin_amdgcn_mfma_f32_16x16x32_bf16(kf1, qf1, s, 0, 0, 0);
                        const int t0 = kt * 64 + nt * 16 + quad * 4;
                        const bool mq = amq != 0;
                        const bool ok0 = amk4.x && mq && (t0 + 0 <= qrow);
                        const bool ok1 = amk4.y && mq && (t0 + 1 <= qrow);
                        const bool ok2 = amk4.z && mq && (t0 + 2 <= qrow);
                        const bool ok3 = amk4.w && mq && (t0 + 3 <= qrow);
                        const float e0 = exp2f(fminf(ok0 ? s[0] : NEG_BIG, 40.f));
                        const float e1 = exp2f(fminf(ok1 ? s[1] : NEG_BIG, 40.f));
                        const float e2 = exp2f(fminf(ok2 ? s[2] : NEG_BIG, 40.f));
                        const float e3 = exp2f(fminf(ok3 ? s[3] : NEG_BIG, 40.f));
                        l_lane += (e0 + e1) + (e2 + e3);
                        uint2 pv;
                        pv.x = cvtpk(e0, e1); pv.y = cvtpk(e2, e3);
                        *(uint2*)&Ps[wq][lm * 72 + nt * 16 + quad * 4] = pv;
                    }
                }

                // ---- O^T += V^T P^T (swapped): regs = 4 consecutive hd ----
                const short8 af0 = *(const short8*)&Ps[wq][lm * 72 + quad * 8];
                const short8 af1 = *(const short8*)&Ps[wq][lm * 72 + 32 + quad * 8];
#pragma unroll
                for (int n2 = 0; n2 < 4; ++n2) {
                    const short8 vf0 = *(const short8*)&Vts[(n2 * 16 + lm) * 72 + quad * 8];
                    const short8 vf1 = *(const short8*)&Vts[(n2 * 16 + lm) * 72 + 32 + quad * 8];
                    o_acc[n2] = __builtin_amdgcn_mfma_f32_16x16x32_bf16(
                        vf0, af0, o_acc[n2], 0, 0, 0);
                    o_acc[n2] = __builtin_amdgcn_mfma_f32_16x16x32_bf16(
                        vf1, af1, o_acc[n2], 0, 0, 0);
                }

                if (have_nxt) {
                    __syncthreads();  // all waves done reading Ks/Vts/amk_s
                    *(uint4*)&Ks[sr * 72 + sc] = kra;
                    *(uint4*)&Ks[sr * 72 + sc + 8] = krb;
                    *(uint4*)&Vts[sr * 72 + sc] = vra;
                    *(uint4*)&Vts[sr * 72 + sc + 8] = vrb;
                    if (tid < 64) amk_s[tid] = amr;
                    __syncthreads();  // next tile ready
                }
            }
        }

        // ---- epilogue: l reduce + unnormalized O ----
        float l = l_lane;
        l += __shfl_xor(l, 16);
        l += __shfl_xor(l, 32);
        if (quad == 0)
            lbuf[(size_t)split * (BB * HH * SS) + (size_t)bh * SS + qrow] = l;
#pragma unroll
        for (int n2 = 0; n2 < 4; ++n2) {
            uint2 v;
            v.x = cvtpk(o_acc[n2][0], o_acc[n2][1]);
            v.y = cvtpk(o_acc[n2][2], o_acc[n2][3]);
            *(uint2*)(Opart + (size_t)split * (BB * SS * DD)
                        + ((size_t)(b * SS + qrow)) * DD + h * HDD + n2 * 16 + quad * 4) = v;
        }
    }
}

// ---------------- combine: A = (O0 + O1) / (l0 + l1), bf16 ----------------
__global__ __launch_bounds__(256) void combine(
    const ushort* __restrict__ Opart, const float* __restrict__ lbuf,
    ushort* __restrict__ Aout)
{
    const size_t e = ((size_t)blockIdx.x * 256 + threadIdx.x) * 8;
    const int m = (int)(e >> 10);
    const int col = (int)(e & 1023);
    const int b = m >> 11, s = m & 2047, h = col >> 6;
    const float l = lbuf[(b * HH + h) * SS + s]
                  + lbuf[BB * HH * SS + (b * HH + h) * SS + s];
    const float inv = l > 0.f ? 1.f / l : 0.f;
    const uint4 u0 = *(const uint4*)(Opart + e);
    const uint4 u1 = *(const uint4*)(Opart + (size_t)BB * SS * DD + e);
    float f0[8], f1[8];
    unpack8(u0, f0);
    unpack8(u1, f1);
    uint4 o;
    o.x = pk2((f0[0] + f1[0]) * inv, (f0[1] + f1[1]) * inv);
    o.y = pk2((f0[2] + f1[2]) * inv, (f0[3] + f1[3]) * inv);
    o.z = pk2((f0[4] + f1[4]) * inv, (f0[5] + f1[5]) * inv);
    o.w = pk2((f0[6] + f1[6]) * inv, (f0[7] + f1[7]) * inv);
    *(uint4*)(Aout + e) = o;
}

extern "C" void kernel_launch(void* const* d_in, const int* in_sizes, int n_in,
                              void* d_out, int out_size, void* d_ws, size_t ws_size,
                              hipStream_t stream) {
    const float* x  = (const float*)d_in[0];
    const int*   am = (const int*)d_in[1];
    const float* Wq = (const float*)d_in[2];
    const float* bq = (const float*)d_in[3];
    const float* Wk = (const float*)d_in[4];
    const float* bk = (const float*)d_in[5];
    const float* Wv = (const float*)d_in[6];
    const float* bv = (const float*)d_in[7];
    const float* Wp = (const float*)d_in[8];
    const float* bp = (const float*)d_in[9];
    float* out = (float*)d_out;

    const size_t elems = (size_t)BB * HH * SS * HDD;  // 4M
    ushort* q_ws = (ushort*)d_ws;                 // Q; later combined A
    ushort* k_ws = q_ws + elems;
    ushort* v_ws = k_ws + elems;                  // V^T (B,H,HD,S)
    float*  lbuf = (float*)(v_ws + elems);        // 2 x 256 KB in a_ws slot
    ushort* wpb  = (ushort*)(lbuf + 2 * BB * HH * SS);  // bf16 Wp (2 MB)

    // d_out scratch: bf16 x (4M) + Wq/Wk/Wv (1M each); later attn partials
    ushort* xb  = (ushort*)d_out;
    ushort* wqb = xb + 4194304;
    ushort* wkb = wqb + 1048576;
    ushort* wvb = wkb + 1048576;

    cvt_all<<<4096, 256, 0, stream>>>(x, Wq, Wk, Wv, Wp, xb, wpb);

    gemm_qkv_wa<<<dim3(32, 8, 3), 256, 0, stream>>>(
        xb, wqb, wkb, wvb, bq, bk, bv, q_ws, k_ws, v_ws);

    attn_mfma<<<dim3(16, BB * HH, 2), 256, 0, stream>>>(
        q_ws, k_ws, v_ws, am, (ushort*)d_out, lbuf);

    combine<<<2048, 256, 0, stream>>>((const ushort*)d_out, lbuf, q_ws);

    gemm_proj_rs<<<dim3(32, 8), 256, 0, stream>>>(q_ws, wpb, bp, out);
}